// Round 4
// baseline (39736.319 us; speedup 1.0000x reference)
//
#include <hip/hip_runtime.h>
#include <hip/hip_bf16.h>

#define SEQ 512
#define HD 1024
#define NWG 256
#define TPB 256
#define LDS_RED_OFF 131072
#define LDS_BYTES (131072 + 24576)
#define OUT_H 33554432ull
#define OUT_C 33619968ull

typedef __bf16 bf16x8 __attribute__((ext_vector_type(8)));
typedef float f32x4 __attribute__((ext_vector_type(4)));

__device__ __forceinline__ unsigned short f2bf(float f) {
  __hip_bfloat16 b = __float2bfloat16(f);  // RNE
  return __builtin_bit_cast(unsigned short, b);
}
__device__ __forceinline__ float bf2f(unsigned short s) {
  return __builtin_bit_cast(float, (unsigned)s << 16);  // exact widen
}

__device__ __forceinline__ float sigm(float v) { return 1.f / (1.f + __expf(-v)); }
__device__ __forceinline__ float tanh_(float v) {
  float av = fabsf(v);
  float e = __expf(-2.f * av);
  float t = (1.f - e) / (1.f + e);
  return copysignf(t, v);
}

// split 8 consecutive fp32 into bf16 hi/lo fragment pair
__device__ __forceinline__ void split8(const float* ap, bf16x8& ah, bf16x8& al) {
  const float4 f0 = *(const float4*)ap;
  const float4 f1 = *(const float4*)(ap + 4);
  union { unsigned short s[8]; uint4 v; } uh, ul;
  const float e[8] = {f0.x, f0.y, f0.z, f0.w, f1.x, f1.y, f1.z, f1.w};
#pragma unroll
  for (int i = 0; i < 8; ++i) {
    const unsigned short hb = f2bf(e[i]);
    uh.s[i] = hb;
    ul.s[i] = f2bf(e[i] - bf2f(hb));
  }
  ah = __builtin_bit_cast(bf16x8, uh.v);
  al = __builtin_bit_cast(bf16x8, ul.v);
}

// two-level grid barrier: 8 groups x 32 WGs, then 8 group-leaders.
__device__ __forceinline__ void grid_barrier2(unsigned* bar, int grp) {
  __syncthreads();
  if (threadIdx.x == 0) {
    __threadfence();  // release my h/out writes to device scope
    unsigned* cx = bar + grp * 32;
    unsigned* gx = bar + grp * 32 + 16;
    unsigned* cG = bar + 256;
    unsigned* gG = bar + 272;
    const unsigned g = __hip_atomic_load(gx, __ATOMIC_RELAXED, __HIP_MEMORY_SCOPE_AGENT);
    const unsigned n = __hip_atomic_fetch_add(cx, 1u, __ATOMIC_ACQ_REL, __HIP_MEMORY_SCOPE_AGENT);
    if (n == 31) {  // last WG of this group
      const unsigned G = __hip_atomic_load(gG, __ATOMIC_RELAXED, __HIP_MEMORY_SCOPE_AGENT);
      const unsigned m = __hip_atomic_fetch_add(cG, 1u, __ATOMIC_ACQ_REL, __HIP_MEMORY_SCOPE_AGENT);
      if (m == 7) {  // last group
        __hip_atomic_store(cG, 0u, __ATOMIC_RELAXED, __HIP_MEMORY_SCOPE_AGENT);
        __hip_atomic_store(gG, G + 1u, __ATOMIC_RELEASE, __HIP_MEMORY_SCOPE_AGENT);
      } else {
        while (__hip_atomic_load(gG, __ATOMIC_ACQUIRE, __HIP_MEMORY_SCOPE_AGENT) == G)
          __builtin_amdgcn_s_sleep(1);
      }
      __hip_atomic_store(cx, 0u, __ATOMIC_RELAXED, __HIP_MEMORY_SCOPE_AGENT);
      __hip_atomic_store(gx, g + 1u, __ATOMIC_RELEASE, __HIP_MEMORY_SCOPE_AGENT);
    } else {
      while (__hip_atomic_load(gx, __ATOMIC_ACQUIRE, __HIP_MEMORY_SCOPE_AGENT) == g)
        __builtin_amdgcn_s_sleep(1);
    }
    __threadfence();  // acquire before reading other WGs' h
  }
  __syncthreads();
}

// 3-product split-bf16 K-loop: acc += Whi*Ahi + Whi*Alo + Wlo*Ahi.
template <bool XF>
__device__ __forceinline__ void gemm_kloop(
    const char* smem, const float* Ax,
    const unsigned short* Ahi, const unsigned short* Alo,
    unsigned bx, unsigned sw, int krel, int cl, int kfrag,
    const uint4 (&wlo)[32], f32x4 (&acc)[4][2]) {
  const float* axp[4];
  const unsigned short* ahp[4];
  const unsigned short* alp[4];
#pragma unroll
  for (int mt = 0; mt < 4; ++mt) {
    const int row = (mt << 4) + cl;
    if constexpr (XF) {
      axp[mt] = Ax + (size_t)row * (SEQ * HD) + (krel + kfrag);
    } else {
      ahp[mt] = Ahi + ((row << 10) + krel + kfrag);
      alp[mt] = Alo + ((row << 10) + krel + kfrag);
    }
  }
#pragma unroll
  for (int ks = 0; ks < 16; ++ks) {
    const unsigned boff = (bx + (unsigned)(ks << 6)) ^ sw;  // XOR after full sum
    const bf16x8 bh0 = __builtin_bit_cast(bf16x8, *(const uint4*)(smem + boff));
    const bf16x8 bh1 = __builtin_bit_cast(bf16x8, *(const uint4*)(smem + boff + 65536));
    const bf16x8 bl0 = __builtin_bit_cast(bf16x8, wlo[2 * ks]);
    const bf16x8 bl1 = __builtin_bit_cast(bf16x8, wlo[2 * ks + 1]);
#pragma unroll
    for (int mt = 0; mt < 4; ++mt) {
      bf16x8 ah, al;
      if constexpr (XF) {
        split8(axp[mt] + (ks << 5), ah, al);
      } else {
        ah = __builtin_bit_cast(bf16x8, *(const uint4*)(ahp[mt] + (ks << 5)));
        al = __builtin_bit_cast(bf16x8, *(const uint4*)(alp[mt] + (ks << 5)));
      }
      acc[mt][0] = __builtin_amdgcn_mfma_f32_16x16x32_bf16(ah, bh0, acc[mt][0], 0, 0, 0);
      acc[mt][1] = __builtin_amdgcn_mfma_f32_16x16x32_bf16(ah, bh1, acc[mt][1], 0, 0, 0);
      acc[mt][0] = __builtin_amdgcn_mfma_f32_16x16x32_bf16(al, bh0, acc[mt][0], 0, 0, 0);
      acc[mt][1] = __builtin_amdgcn_mfma_f32_16x16x32_bf16(al, bh1, acc[mt][1], 0, 0, 0);
      acc[mt][0] = __builtin_amdgcn_mfma_f32_16x16x32_bf16(ah, bl0, acc[mt][0], 0, 0, 0);
      acc[mt][1] = __builtin_amdgcn_mfma_f32_16x16x32_bf16(ah, bl1, acc[mt][1], 0, 0, 0);
    }
  }
}

// Persistent LSTM. WG w: layer=w>>7, owns 8 hidden units (all 4 gates = 32 cols).
// Phase p: layer0 does t=p, layer1 does t=p-1; one grid barrier per phase.
// STATIC shared memory (152 KB) + PLAIN launch: no cooperative API, no dynamic-LDS
// attribute path. 256 WGs at 1 WG/CU on 256 CUs are de-facto co-resident.
__global__ __launch_bounds__(TPB, 1) void lstm_main(
    const float* __restrict__ x,
    const float* __restrict__ Wih_f,
    const float* __restrict__ Whh_f,
    const float* __restrict__ bias,
    unsigned short* h0hi, unsigned short* h0lo,
    unsigned short* h1hi, unsigned short* h1lo,
    float* __restrict__ out,
    unsigned* bar) {
  __shared__ char smem[LDS_BYTES];
  float* red = (float*)(smem + LDS_RED_OFF);

  const int w = blockIdx.x;
  const int tid = threadIdx.x;
  const int layer = w >> 7;
  const int j0 = (w & 127) << 3;
  const int lane = tid & 63;
  const int kw = tid >> 6;
  const int cl = lane & 15;
  const int rg = lane >> 4;
  const int kfrag = rg << 3;
  const int kbase = kw << 9;
  const int krel = (kw & 1) << 9;
  const unsigned sw = (unsigned)((cl & 7) << 4);
  const unsigned bx = ((unsigned)cl << 12) + ((unsigned)(kbase + kfrag) << 1);  // unswizzled

  // ---- prologue 1: stage W_hi (bf16 of fp32 W) into LDS, XOR-swizzled
  {
    const int c = tid >> 3, sub = tid & 7;
    const int grow = ((c >> 3) << 10) + j0 + (c & 7);
    const float* s0 = Wih_f + ((size_t)layer << 22) + (size_t)grow * HD;
    const float* s1 = Whh_f + ((size_t)layer << 22) + (size_t)grow * HD;
    const unsigned cbase = (unsigned)c << 12;
    const unsigned cx = (unsigned)((c & 7) << 4);
    for (int kk = sub * 256; kk < sub * 256 + 256; kk += 8) {
      const float* sp = (kk < HD) ? (s0 + kk) : (s1 + (kk - HD));
      const float4 f0 = *(const float4*)sp;
      const float4 f1 = *(const float4*)(sp + 4);
      union { unsigned short s[8]; uint4 v; } u;
      u.s[0] = f2bf(f0.x); u.s[1] = f2bf(f0.y); u.s[2] = f2bf(f0.z); u.s[3] = f2bf(f0.w);
      u.s[4] = f2bf(f1.x); u.s[5] = f2bf(f1.y); u.s[6] = f2bf(f1.z); u.s[7] = f2bf(f1.w);
      *(uint4*)(smem + ((cbase + ((unsigned)kk << 1)) ^ cx)) = u.v;
    }
  }

  // ---- prologue 2: build this lane's W_lo B-fragments directly from fp32 W
  // fragment i (nt=i&1, ks=i>>1): col c=nt*16+cl, k = kbase + ks*32 + kfrag .. +7
  uint4 wlo[32];
  {
#pragma unroll
    for (int i = 0; i < 32; ++i) {
      const int nt = i & 1, ks = i >> 1;
      const int c = nt * 16 + cl;
      const int grow = ((c >> 3) << 10) + j0 + (c & 7);
      const int kglob = kbase + (ks << 5) + kfrag;
      const float* src = (kglob < HD)
          ? (Wih_f + (((size_t)layer << 22) + ((size_t)grow << 10) + kglob))
          : (Whh_f + (((size_t)layer << 22) + ((size_t)grow << 10) + (kglob - HD)));
      union { unsigned short s[8]; uint4 v; } u;
#pragma unroll
      for (int e = 0; e < 8; ++e) {
        const float vv = src[e];
        const unsigned short hb = f2bf(vv);
        u.s[e] = f2bf(vv - bf2f(hb));
      }
      wlo[i] = u.v;
    }
  }

  const int u_ = cl & 7;
  const float bi  = bias[(layer << 12) + j0 + u_];
  const float bf_ = bias[(layer << 12) + 1024 + j0 + u_];
  const float bg  = bias[(layer << 12) + 2048 + j0 + u_];
  const float bo  = bias[(layer << 12) + 3072 + j0 + u_];

  float creg[16];
#pragma unroll
  for (int i = 0; i < 16; ++i) creg[i] = 0.f;

  __syncthreads();

  for (int p = 0; p <= SEQ; ++p) {
    const bool active = layer ? (p >= 1) : (p < SEQ);
    if (active) {
      const int t = layer ? (p - 1) : p;
      const float* Ax = nullptr;
      const unsigned short *Ahi = nullptr, *Alo = nullptr;
      if (layer == 0) {
        if (kw < 2) {
          Ax = x + (size_t)t * HD;
        } else {
          const int par = (t + 1) & 1;
          Ahi = h0hi + (par << 16); Alo = h0lo + (par << 16);
        }
      } else {
        if (kw < 2) {
          const int par = t & 1;
          Ahi = h0hi + (par << 16); Alo = h0lo + (par << 16);
        } else {
          const int par = (t + 1) & 1;
          Ahi = h1hi + (par << 16); Alo = h1lo + (par << 16);
        }
      }

      f32x4 acc[4][2];
#pragma unroll
      for (int mt = 0; mt < 4; ++mt) {
        acc[mt][0] = (f32x4){0.f, 0.f, 0.f, 0.f};
        acc[mt][1] = (f32x4){0.f, 0.f, 0.f, 0.f};
      }
      if (layer == 0 && kw < 2) gemm_kloop<true>(smem, Ax, nullptr, nullptr, bx, sw, krel, cl, kfrag, wlo, acc);
      else                      gemm_kloop<false>(smem, nullptr, Ahi, Alo, bx, sw, krel, cl, kfrag, wlo, acc);

      // ---- cross-wave K-reduction
      __syncthreads();
      if (kw >= 1) {
        float* rp = red + (((kw - 1) << 11) + lane);
#pragma unroll
        for (int mt = 0; mt < 4; ++mt)
#pragma unroll
          for (int nt = 0; nt < 2; ++nt)
#pragma unroll
            for (int r = 0; r < 4; ++r)
              rp[((mt << 3) + (nt << 2) + r) << 6] = acc[mt][nt][r];
      }
      __syncthreads();
      if (kw == 0) {
#pragma unroll
        for (int mt = 0; mt < 4; ++mt)
#pragma unroll
          for (int nt = 0; nt < 2; ++nt)
#pragma unroll
            for (int r = 0; r < 4; ++r) {
              const int idx = ((mt << 3) + (nt << 2) + r) << 6;
              acc[mt][nt][r] += red[idx + lane] + red[2048 + idx + lane] + red[4096 + idx + lane];
            }
        // ---- pointwise (lanes cl and cl^8 duplicate consistently)
        unsigned short* hhi_d = (layer ? h1hi : h0hi) + ((t & 1) << 16);
        unsigned short* hlo_d = (layer ? h1lo : h0lo) + ((t & 1) << 16);
#pragma unroll
        for (int mt = 0; mt < 4; ++mt) {
#pragma unroll
          for (int r = 0; r < 4; ++r) {
            const float a0 = acc[mt][0][r], a1 = acc[mt][1][r];
            const float a0x = __shfl_xor(a0, 8);
            const float a1x = __shfl_xor(a1, 8);
            const bool lo = (cl < 8);
            const float vi = (lo ? a0 : a0x) + bi;
            const float vf = (lo ? a0x : a0) + bf_;
            const float vg = (lo ? a1 : a1x) + bg;
            const float vo = (lo ? a1x : a1) + bo;
            const float ig = sigm(vi), fg = sigm(vf), gg = tanh_(vg), og = sigm(vo);
            const int ci = (mt << 2) + r;
            const float cn = fg * creg[ci] + ig * gg;
            creg[ci] = cn;
            const float h = og * tanh_(cn);
            if (lo) {
              const int b = (mt << 4) + (rg << 2) + r;
              const int hidx = (b << 10) + j0 + u_;
              const unsigned short hb = f2bf(h);
              hhi_d[hidx] = hb;
              hlo_d[hidx] = f2bf(h - bf2f(hb));
              if (layer) {
                out[((size_t)b * SEQ + t) * HD + j0 + u_] = h;
                if (t == SEQ - 1) {
                  out[OUT_H + (size_t)(b << 10) + j0 + u_] = h;
                  out[OUT_C + (size_t)(b << 10) + j0 + u_] = cn;
                }
              }
            }
          }
        }
      }
    }
    if (p != SEQ) grid_barrier2(bar, w & 7);
  }
}

// prep: combined bias, zero h bufs + barrier (every call -- ws is poisoned 0xAA)
__global__ void lstm_prep(const float* __restrict__ bih, const float* __restrict__ bhh,
                          float* __restrict__ bias,
                          unsigned short* __restrict__ h0hi, unsigned short* __restrict__ h0lo,
                          unsigned short* __restrict__ h1hi, unsigned short* __restrict__ h1lo,
                          unsigned* __restrict__ bar) {
  const size_t i0 = (size_t)blockIdx.x * blockDim.x + threadIdx.x;
  const size_t stride = (size_t)gridDim.x * blockDim.x;
  for (size_t idx = i0; idx < 8192; idx += stride) bias[idx] = bih[idx] + bhh[idx];
  const ushort4 z = make_ushort4(0, 0, 0, 0);
  for (size_t idx = i0; idx < 32768; idx += stride) {
    ((ushort4*)h0hi)[idx] = z; ((ushort4*)h0lo)[idx] = z;
    ((ushort4*)h1hi)[idx] = z; ((ushort4*)h1lo)[idx] = z;
  }
  for (size_t idx = i0; idx < 512; idx += stride) bar[idx] = 0u;
}

extern "C" void kernel_launch(void* const* d_in, const int* in_sizes, int n_in,
                              void* d_out, int out_size, void* d_ws, size_t ws_size,
                              hipStream_t stream) {
  const float* x     = (const float*)d_in[0];
  const float* Wih_f = (const float*)d_in[1];
  const float* bih   = (const float*)d_in[2];
  const float* Whh_f = (const float*)d_in[3];
  const float* bhh   = (const float*)d_in[4];
  float* out = (float*)d_out;

  char* ws = (char*)d_ws;                                     // ~1.1 MB used
  float* bias           = (float*)(ws);                       // 32 KB
  unsigned short* h0hi  = (unsigned short*)(ws + 32768);      // 256 KB each (2 parities)
  unsigned short* h0lo  = (unsigned short*)(ws + 32768 + 262144);
  unsigned short* h1hi  = (unsigned short*)(ws + 32768 + 2 * 262144);
  unsigned short* h1lo  = (unsigned short*)(ws + 32768 + 3 * 262144);
  unsigned* bar         = (unsigned*)(ws + 32768 + 4 * 262144);  // 2 KB

  hipLaunchKernelGGL(lstm_prep, dim3(256), dim3(256), 0, stream,
                     bih, bhh, bias, h0hi, h0lo, h1hi, h1lo, bar);

  hipLaunchKernelGGL(lstm_main, dim3(NWG), dim3(TPB), 0, stream,
                     x, Wih_f, Whh_f, bias, h0hi, h0lo, h1hi, h1lo, out, bar);
}

// Round 5
// 17648.901 us; speedup vs baseline: 2.2515x; 2.2515x over previous
//
#include <hip/hip_runtime.h>
#include <hip/hip_bf16.h>

#define SEQ 512
#define HD 1024
#define NWG 256
#define TPB 256
#define LDS_RED_OFF 131072
#define LDS_BYTES (131072 + 24576)
#define OUT_H 33554432ull
#define OUT_C 33619968ull

typedef __bf16 bf16x8 __attribute__((ext_vector_type(8)));
typedef float f32x4 __attribute__((ext_vector_type(4)));

__device__ __forceinline__ unsigned short f2bf(float f) {
  __hip_bfloat16 b = __float2bfloat16(f);  // RNE
  return __builtin_bit_cast(unsigned short, b);
}
__device__ __forceinline__ float bf2f(unsigned short s) {
  return __builtin_bit_cast(float, (unsigned)s << 16);  // exact widen
}

__device__ __forceinline__ float sigm(float v) { return 1.f / (1.f + __expf(-v)); }
__device__ __forceinline__ float tanh_(float v) {
  float av = fabsf(v);
  float e = __expf(-2.f * av);
  float t = (1.f - e) / (1.f + e);
  return copysignf(t, v);
}

// split 8 consecutive fp32 into bf16 hi/lo fragment pair
__device__ __forceinline__ void split8(const float* ap, bf16x8& ah, bf16x8& al) {
  const float4 f0 = *(const float4*)ap;
  const float4 f1 = *(const float4*)(ap + 4);
  union { unsigned short s[8]; uint4 v; } uh, ul;
  const float e[8] = {f0.x, f0.y, f0.z, f0.w, f1.x, f1.y, f1.z, f1.w};
#pragma unroll
  for (int i = 0; i < 8; ++i) {
    const unsigned short hb = f2bf(e[i]);
    uh.s[i] = hb;
    ul.s[i] = f2bf(e[i] - bf2f(hb));
  }
  ah = __builtin_bit_cast(bf16x8, uh.v);
  al = __builtin_bit_cast(bf16x8, ul.v);
}

// Flag-array grid barrier (round-4 perf fix). WG i RELAXED-stores its epoch to
// its own 128B line (sc1 bypass, no cache maintenance); WG0's 256 threads poll
// the 256 flags in parallel, then publish `go`. Exactly one release fence and
// one acquire fence per WG per phase -- no atomic RMWs, no per-poll buffer_inv.
__device__ __forceinline__ void grid_barrier_flags(unsigned* flags, unsigned* go,
                                                   int w, unsigned e) {
  __syncthreads();
  if (w == 0) {
    const int i = threadIdx.x;
    if (i != 0) {
      while (__hip_atomic_load(flags + i * 32, __ATOMIC_RELAXED, __HIP_MEMORY_SCOPE_AGENT) < e)
        __builtin_amdgcn_s_sleep(1);
    }
    __syncthreads();
    if (i == 0) {
      __builtin_amdgcn_fence(__ATOMIC_RELEASE, "agent");  // order my writes + flag-reads before go
      __hip_atomic_store(go, e, __ATOMIC_RELAXED, __HIP_MEMORY_SCOPE_AGENT);
      __builtin_amdgcn_fence(__ATOMIC_ACQUIRE, "agent");  // invalidate before reading others' h
    }
  } else {
    if (threadIdx.x == 0) {
      __builtin_amdgcn_fence(__ATOMIC_RELEASE, "agent");  // flush my h/out writes
      __hip_atomic_store(flags + w * 32, e, __ATOMIC_RELAXED, __HIP_MEMORY_SCOPE_AGENT);
      while (__hip_atomic_load(go, __ATOMIC_RELAXED, __HIP_MEMORY_SCOPE_AGENT) < e)
        __builtin_amdgcn_s_sleep(1);
      __builtin_amdgcn_fence(__ATOMIC_ACQUIRE, "agent");
    }
  }
  __syncthreads();
}

// 3-product split-bf16 K-loop: acc += Whi*Ahi + Whi*Alo + Wlo*Ahi.
template <bool XF>
__device__ __forceinline__ void gemm_kloop(
    const char* smem, const float* Ax,
    const unsigned short* Ahi, const unsigned short* Alo,
    unsigned bx, unsigned sw, int krel, int cl, int kfrag,
    const uint4 (&wlo)[32], f32x4 (&acc)[4][2]) {
  const float* axp[4];
  const unsigned short* ahp[4];
  const unsigned short* alp[4];
#pragma unroll
  for (int mt = 0; mt < 4; ++mt) {
    const int row = (mt << 4) + cl;
    if constexpr (XF) {
      axp[mt] = Ax + (size_t)row * (SEQ * HD) + (krel + kfrag);
    } else {
      ahp[mt] = Ahi + ((row << 10) + krel + kfrag);
      alp[mt] = Alo + ((row << 10) + krel + kfrag);
    }
  }
#pragma unroll
  for (int ks = 0; ks < 16; ++ks) {
    const unsigned boff = (bx + (unsigned)(ks << 6)) ^ sw;  // XOR after full sum
    const bf16x8 bh0 = __builtin_bit_cast(bf16x8, *(const uint4*)(smem + boff));
    const bf16x8 bh1 = __builtin_bit_cast(bf16x8, *(const uint4*)(smem + boff + 65536));
    const bf16x8 bl0 = __builtin_bit_cast(bf16x8, wlo[2 * ks]);
    const bf16x8 bl1 = __builtin_bit_cast(bf16x8, wlo[2 * ks + 1]);
#pragma unroll
    for (int mt = 0; mt < 4; ++mt) {
      bf16x8 ah, al;
      if constexpr (XF) {
        split8(axp[mt] + (ks << 5), ah, al);
      } else {
        ah = __builtin_bit_cast(bf16x8, *(const uint4*)(ahp[mt] + (ks << 5)));
        al = __builtin_bit_cast(bf16x8, *(const uint4*)(alp[mt] + (ks << 5)));
      }
      acc[mt][0] = __builtin_amdgcn_mfma_f32_16x16x32_bf16(ah, bh0, acc[mt][0], 0, 0, 0);
      acc[mt][1] = __builtin_amdgcn_mfma_f32_16x16x32_bf16(ah, bh1, acc[mt][1], 0, 0, 0);
      acc[mt][0] = __builtin_amdgcn_mfma_f32_16x16x32_bf16(al, bh0, acc[mt][0], 0, 0, 0);
      acc[mt][1] = __builtin_amdgcn_mfma_f32_16x16x32_bf16(al, bh1, acc[mt][1], 0, 0, 0);
      acc[mt][0] = __builtin_amdgcn_mfma_f32_16x16x32_bf16(ah, bl0, acc[mt][0], 0, 0, 0);
      acc[mt][1] = __builtin_amdgcn_mfma_f32_16x16x32_bf16(ah, bl1, acc[mt][1], 0, 0, 0);
    }
  }
}

// Persistent LSTM. WG w: layer=w>>7, owns 8 hidden units (all 4 gates = 32 cols).
// Phase p: layer0 does t=p, layer1 does t=p-1; one grid barrier per phase.
// XCONV: x pre-split into bf16 hi/lo t-major panels (xhi/xlo), else split on the fly.
template <bool XCONV>
__global__ __launch_bounds__(TPB, 1) void lstm_main(
    const float* __restrict__ x,
    const unsigned short* __restrict__ xhi,
    const unsigned short* __restrict__ xlo,
    const float* __restrict__ Wih_f,
    const float* __restrict__ Whh_f,
    const float* __restrict__ bias,
    unsigned short* h0hi, unsigned short* h0lo,
    unsigned short* h1hi, unsigned short* h1lo,
    float* __restrict__ out,
    unsigned* flags, unsigned* go) {
  __shared__ char smem[LDS_BYTES];
  float* red = (float*)(smem + LDS_RED_OFF);

  const int w = blockIdx.x;
  const int tid = threadIdx.x;
  const int layer = w >> 7;
  const int j0 = (w & 127) << 3;
  const int lane = tid & 63;
  const int kw = tid >> 6;
  const int cl = lane & 15;
  const int rg = lane >> 4;
  const int kfrag = rg << 3;
  const int kbase = kw << 9;
  const int krel = (kw & 1) << 9;
  const unsigned sw = (unsigned)((cl & 7) << 4);
  const unsigned bx = ((unsigned)cl << 12) + ((unsigned)(kbase + kfrag) << 1);  // unswizzled

  // ---- prologue 1: stage W_hi (bf16 of fp32 W) into LDS, XOR-swizzled
  {
    const int c = tid >> 3, sub = tid & 7;
    const int grow = ((c >> 3) << 10) + j0 + (c & 7);
    const float* s0 = Wih_f + ((size_t)layer << 22) + (size_t)grow * HD;
    const float* s1 = Whh_f + ((size_t)layer << 22) + (size_t)grow * HD;
    const unsigned cbase = (unsigned)c << 12;
    const unsigned cx = (unsigned)((c & 7) << 4);
    for (int kk = sub * 256; kk < sub * 256 + 256; kk += 8) {
      const float* sp = (kk < HD) ? (s0 + kk) : (s1 + (kk - HD));
      const float4 f0 = *(const float4*)sp;
      const float4 f1 = *(const float4*)(sp + 4);
      union { unsigned short s[8]; uint4 v; } u;
      u.s[0] = f2bf(f0.x); u.s[1] = f2bf(f0.y); u.s[2] = f2bf(f0.z); u.s[3] = f2bf(f0.w);
      u.s[4] = f2bf(f1.x); u.s[5] = f2bf(f1.y); u.s[6] = f2bf(f1.z); u.s[7] = f2bf(f1.w);
      *(uint4*)(smem + ((cbase + ((unsigned)kk << 1)) ^ cx)) = u.v;
    }
  }

  // ---- prologue 2: build this lane's W_lo B-fragments directly from fp32 W
  uint4 wlo[32];
  {
#pragma unroll
    for (int i = 0; i < 32; ++i) {
      const int nt = i & 1, ks = i >> 1;
      const int c = nt * 16 + cl;
      const int grow = ((c >> 3) << 10) + j0 + (c & 7);
      const int kglob = kbase + (ks << 5) + kfrag;
      const float* src = (kglob < HD)
          ? (Wih_f + (((size_t)layer << 22) + ((size_t)grow << 10) + kglob))
          : (Whh_f + (((size_t)layer << 22) + ((size_t)grow << 10) + (kglob - HD)));
      union { unsigned short s[8]; uint4 v; } u;
#pragma unroll
      for (int e = 0; e < 8; ++e) {
        const float vv = src[e];
        const unsigned short hb = f2bf(vv);
        u.s[e] = f2bf(vv - bf2f(hb));
      }
      wlo[i] = u.v;
    }
  }

  const int u_ = cl & 7;
  const float bi  = bias[(layer << 12) + j0 + u_];
  const float bf_ = bias[(layer << 12) + 1024 + j0 + u_];
  const float bg  = bias[(layer << 12) + 2048 + j0 + u_];
  const float bo  = bias[(layer << 12) + 3072 + j0 + u_];

  float creg[16];
#pragma unroll
  for (int i = 0; i < 16; ++i) creg[i] = 0.f;

  __syncthreads();

  for (int p = 0; p <= SEQ; ++p) {
    const bool active = layer ? (p >= 1) : (p < SEQ);
    if (active) {
      const int t = layer ? (p - 1) : p;

      f32x4 acc[4][2];
#pragma unroll
      for (int mt = 0; mt < 4; ++mt) {
        acc[mt][0] = (f32x4){0.f, 0.f, 0.f, 0.f};
        acc[mt][1] = (f32x4){0.f, 0.f, 0.f, 0.f};
      }

      if (layer == 0) {
        if (kw < 2) {
          if constexpr (XCONV)
            gemm_kloop<false>(smem, nullptr, xhi + ((size_t)t << 16), xlo + ((size_t)t << 16),
                              bx, sw, krel, cl, kfrag, wlo, acc);
          else
            gemm_kloop<true>(smem, x + (size_t)t * HD, nullptr, nullptr,
                             bx, sw, krel, cl, kfrag, wlo, acc);
        } else {
          const int par = (t + 1) & 1;
          gemm_kloop<false>(smem, nullptr, h0hi + (par << 16), h0lo + (par << 16),
                            bx, sw, krel, cl, kfrag, wlo, acc);
        }
      } else {
        if (kw < 2) {
          const int par = t & 1;
          gemm_kloop<false>(smem, nullptr, h0hi + (par << 16), h0lo + (par << 16),
                            bx, sw, krel, cl, kfrag, wlo, acc);
        } else {
          const int par = (t + 1) & 1;
          gemm_kloop<false>(smem, nullptr, h1hi + (par << 16), h1lo + (par << 16),
                            bx, sw, krel, cl, kfrag, wlo, acc);
        }
      }

      // ---- cross-wave K-reduction
      __syncthreads();
      if (kw >= 1) {
        float* rp = red + (((kw - 1) << 11) + lane);
#pragma unroll
        for (int mt = 0; mt < 4; ++mt)
#pragma unroll
          for (int nt = 0; nt < 2; ++nt)
#pragma unroll
            for (int r = 0; r < 4; ++r)
              rp[((mt << 3) + (nt << 2) + r) << 6] = acc[mt][nt][r];
      }
      __syncthreads();
      if (kw == 0) {
#pragma unroll
        for (int mt = 0; mt < 4; ++mt)
#pragma unroll
          for (int nt = 0; nt < 2; ++nt)
#pragma unroll
            for (int r = 0; r < 4; ++r) {
              const int idx = ((mt << 3) + (nt << 2) + r) << 6;
              acc[mt][nt][r] += red[idx + lane] + red[2048 + idx + lane] + red[4096 + idx + lane];
            }
        // ---- pointwise (lanes cl and cl^8 duplicate consistently)
        unsigned short* hhi_d = (layer ? h1hi : h0hi) + ((t & 1) << 16);
        unsigned short* hlo_d = (layer ? h1lo : h0lo) + ((t & 1) << 16);
#pragma unroll
        for (int mt = 0; mt < 4; ++mt) {
#pragma unroll
          for (int r = 0; r < 4; ++r) {
            const float a0 = acc[mt][0][r], a1 = acc[mt][1][r];
            const float a0x = __shfl_xor(a0, 8);
            const float a1x = __shfl_xor(a1, 8);
            const bool lo = (cl < 8);
            const float vi = (lo ? a0 : a0x) + bi;
            const float vf = (lo ? a0x : a0) + bf_;
            const float vg = (lo ? a1 : a1x) + bg;
            const float vo = (lo ? a1x : a1) + bo;
            const float ig = sigm(vi), fg = sigm(vf), gg = tanh_(vg), og = sigm(vo);
            const int ci = (mt << 2) + r;
            const float cn = fg * creg[ci] + ig * gg;
            creg[ci] = cn;
            const float h = og * tanh_(cn);
            if (lo) {
              const int b = (mt << 4) + (rg << 2) + r;
              const int hidx = (b << 10) + j0 + u_;
              const unsigned short hb = f2bf(h);
              hhi_d[hidx] = hb;
              hlo_d[hidx] = f2bf(h - bf2f(hb));
              if (layer) {
                out[((size_t)b * SEQ + t) * HD + j0 + u_] = h;
                if (t == SEQ - 1) {
                  out[OUT_H + (size_t)(b << 10) + j0 + u_] = h;
                  out[OUT_C + (size_t)(b << 10) + j0 + u_] = cn;
                }
              }
            }
          }
        }
      }
    }
    if (p != SEQ) grid_barrier_flags(flags, go, w, (unsigned)(p + 1));
  }
}

// prep: combined bias, zero h bufs + barrier flags (every launch -- ws poisoned)
__global__ void lstm_prep(const float* __restrict__ bih, const float* __restrict__ bhh,
                          float* __restrict__ bias,
                          unsigned short* __restrict__ h0hi, unsigned short* __restrict__ h0lo,
                          unsigned short* __restrict__ h1hi, unsigned short* __restrict__ h1lo,
                          unsigned* __restrict__ bar) {
  const size_t i0 = (size_t)blockIdx.x * blockDim.x + threadIdx.x;
  const size_t stride = (size_t)gridDim.x * blockDim.x;
  for (size_t idx = i0; idx < 8192; idx += stride) bias[idx] = bih[idx] + bhh[idx];
  const ushort4 z = make_ushort4(0, 0, 0, 0);
  for (size_t idx = i0; idx < 32768; idx += stride) {
    ((ushort4*)h0hi)[idx] = z; ((ushort4*)h0lo)[idx] = z;
    ((ushort4*)h1hi)[idx] = z; ((ushort4*)h1lo)[idx] = z;
  }
  for (size_t idx = i0; idx < 8256; idx += stride) bar[idx] = 0u;  // flags (32KB) + go line
}

// convert x[b][t][k] fp32 -> t-major bf16 hi/lo panels xhi/xlo[((t*64+b)<<10)+k]
__global__ void x_convert(const float* __restrict__ x,
                          unsigned short* __restrict__ xhi,
                          unsigned short* __restrict__ xlo) {
  const size_t tidg = (size_t)blockIdx.x * blockDim.x + threadIdx.x;  // 4M threads
  const int k8 = (int)(tidg & 127);          // 128 chunks of 8 along k
  const size_t bt = tidg >> 7;               // 0..32767
  const int b = (int)(bt >> 9);              // bt / 512
  const int t = (int)(bt & 511);             // bt % 512
  const float* src = x + (((size_t)b * SEQ + t) << 10) + (k8 << 3);
  const size_t dst = (((size_t)t * 64 + b) << 10) + (k8 << 3);
  const float4 f0 = *(const float4*)src;
  const float4 f1 = *(const float4*)(src + 4);
  union { unsigned short s[8]; uint4 v; } uh, ul;
  const float e[8] = {f0.x, f0.y, f0.z, f0.w, f1.x, f1.y, f1.z, f1.w};
#pragma unroll
  for (int i = 0; i < 8; ++i) {
    const unsigned short hb = f2bf(e[i]);
    uh.s[i] = hb;
    ul.s[i] = f2bf(e[i] - bf2f(hb));
  }
  *(uint4*)(xhi + dst) = uh.v;
  *(uint4*)(xlo + dst) = ul.v;
}

extern "C" void kernel_launch(void* const* d_in, const int* in_sizes, int n_in,
                              void* d_out, int out_size, void* d_ws, size_t ws_size,
                              hipStream_t stream) {
  const float* x     = (const float*)d_in[0];
  const float* Wih_f = (const float*)d_in[1];
  const float* bih   = (const float*)d_in[2];
  const float* Whh_f = (const float*)d_in[3];
  const float* bhh   = (const float*)d_in[4];
  float* out = (float*)d_out;

  char* ws = (char*)d_ws;
  float* bias           = (float*)(ws);                       // 32 KB
  unsigned short* h0hi  = (unsigned short*)(ws + 32768);      // 256 KB each (2 parities)
  unsigned short* h0lo  = (unsigned short*)(ws + 32768 + 262144);
  unsigned short* h1hi  = (unsigned short*)(ws + 32768 + 2 * 262144);
  unsigned short* h1lo  = (unsigned short*)(ws + 32768 + 3 * 262144);
  unsigned* bar         = (unsigned*)(ws + 32768 + 4 * 262144);  // 32KB flags + go
  unsigned* flags       = bar;
  unsigned* go          = bar + 8192;
  unsigned short* xhi   = (unsigned short*)(ws + (2ull << 20));            // 64 MB
  unsigned short* xlo   = (unsigned short*)(ws + (2ull << 20) + (64ull << 20));  // 64 MB

  const bool xc = ws_size >= (2ull << 20) + (128ull << 20) + (1ull << 20);

  hipLaunchKernelGGL(lstm_prep, dim3(256), dim3(256), 0, stream,
                     bih, bhh, bias, h0hi, h0lo, h1hi, h1lo, bar);

  if (xc) {
    hipLaunchKernelGGL(x_convert, dim3(16384), dim3(256), 0, stream, x, xhi, xlo);
    hipLaunchKernelGGL(lstm_main<true>, dim3(NWG), dim3(TPB), 0, stream,
                       x, xhi, xlo, Wih_f, Whh_f, bias, h0hi, h0lo, h1hi, h1lo, out, flags, go);
  } else {
    hipLaunchKernelGGL(lstm_main<false>, dim3(NWG), dim3(TPB), 0, stream,
                       x, xhi, xlo, Wih_f, Whh_f, bias, h0hi, h0lo, h1hi, h1lo, out, flags, go);
  }
}

// Round 6
// 13571.948 us; speedup vs baseline: 2.9278x; 1.3004x over previous
//
#include <hip/hip_runtime.h>
#include <hip/hip_bf16.h>

#define SEQ 512
#define HD 1024
#define NWG 256
#define TPB 512
#define LDS_RED_OFF 131072
#define LDS_BYTES (131072 + 24576)
#define OUT_H 33554432ull
#define OUT_C 33619968ull

typedef __bf16 bf16x8 __attribute__((ext_vector_type(8)));
typedef float f32x4 __attribute__((ext_vector_type(4)));

__device__ __forceinline__ unsigned short f2bf(float f) {
  __hip_bfloat16 b = __float2bfloat16(f);  // RNE
  return __builtin_bit_cast(unsigned short, b);
}
__device__ __forceinline__ float bf2f(unsigned short s) {
  return __builtin_bit_cast(float, (unsigned)s << 16);  // exact widen
}

__device__ __forceinline__ float sigm(float v) { return 1.f / (1.f + __expf(-v)); }
__device__ __forceinline__ float tanh_(float v) {
  float av = fabsf(v);
  float e = __expf(-2.f * av);
  float t = (1.f - e) / (1.f + e);
  return copysignf(t, v);
}

// split 8 consecutive fp32 into bf16 hi/lo fragment pair
__device__ __forceinline__ void split8(const float* ap, bf16x8& ah, bf16x8& al) {
  const float4 f0 = *(const float4*)ap;
  const float4 f1 = *(const float4*)(ap + 4);
  union { unsigned short s[8]; uint4 v; } uh, ul;
  const float e[8] = {f0.x, f0.y, f0.z, f0.w, f1.x, f1.y, f1.z, f1.w};
#pragma unroll
  for (int i = 0; i < 8; ++i) {
    const unsigned short hb = f2bf(e[i]);
    uh.s[i] = hb;
    ul.s[i] = f2bf(e[i] - bf2f(hb));
  }
  ah = __builtin_bit_cast(bf16x8, uh.v);
  al = __builtin_bit_cast(bf16x8, ul.v);
}

// Flag-array grid barrier, ACQUIRE HOISTED (round-5 perf fix): the buffer_inv
// runs inside the barrier window (between arrival and go-poll), so NO cache
// maintenance happens during compute -> A-panels stay L2-shared all phase.
// Correctness: all releases happen-before `go`; between a WG's inv and its
// poll-success it issues only sc-bypassing flag loads (no L2 refills), so
// every post-barrier refill is fetched from L3 after all releases.
__device__ __forceinline__ void grid_barrier_flags(unsigned* flags, unsigned* go,
                                                   int w, unsigned e) {
  __syncthreads();
  if (w == 0) {
    const int i = threadIdx.x;
    if (i == 0) {
      __builtin_amdgcn_fence(__ATOMIC_RELEASE, "agent");  // flush my h/out writes
      __builtin_amdgcn_fence(__ATOMIC_ACQUIRE, "agent");  // inv before post-barrier reads
    }
    if (i > 0 && i < 256) {
      while (__hip_atomic_load(flags + i * 32, __ATOMIC_RELAXED, __HIP_MEMORY_SCOPE_AGENT) < e)
        __builtin_amdgcn_s_sleep(1);
    }
    __syncthreads();
    if (i == 0)
      __hip_atomic_store(go, e, __ATOMIC_RELAXED, __HIP_MEMORY_SCOPE_AGENT);
  } else {
    if (threadIdx.x == 0) {
      __builtin_amdgcn_fence(__ATOMIC_RELEASE, "agent");  // flush my h/out writes
      __hip_atomic_store(flags + w * 32, e, __ATOMIC_RELAXED, __HIP_MEMORY_SCOPE_AGENT);
      __builtin_amdgcn_fence(__ATOMIC_ACQUIRE, "agent");  // inv NOW, while waiting
      while (__hip_atomic_load(go, __ATOMIC_RELAXED, __HIP_MEMORY_SCOPE_AGENT) < e)
        __builtin_amdgcn_s_sleep(1);
    }
  }
  __syncthreads();
}

// 3-product split-bf16 K-loop: acc += Whi*Ahi + Whi*Alo + Wlo*Ahi.
// 8-wave version: each wave owns (K-slice kw, M-half mh): 2 mt tiles.
template <bool XF>
__device__ __forceinline__ void gemm_kloop(
    const char* smem, const float* Ax,
    const unsigned short* Ahi, const unsigned short* Alo,
    unsigned bx, unsigned sw, int krel, int cl, int kfrag, int mbase,
    const uint4 (&wlo)[32], f32x4 (&acc)[2][2]) {
  const float* axp[2];
  const unsigned short* ahp[2];
  const unsigned short* alp[2];
#pragma unroll
  for (int m = 0; m < 2; ++m) {
    const int row = mbase + (m << 4) + cl;
    if constexpr (XF) {
      axp[m] = Ax + (size_t)row * (SEQ * HD) + (krel + kfrag);
    } else {
      ahp[m] = Ahi + ((row << 10) + krel + kfrag);
      alp[m] = Alo + ((row << 10) + krel + kfrag);
    }
  }
#pragma unroll
  for (int ks = 0; ks < 16; ++ks) {
    const unsigned boff = (bx + (unsigned)(ks << 6)) ^ sw;  // XOR after full sum
    const bf16x8 bh0 = __builtin_bit_cast(bf16x8, *(const uint4*)(smem + boff));
    const bf16x8 bh1 = __builtin_bit_cast(bf16x8, *(const uint4*)(smem + boff + 65536));
    const bf16x8 bl0 = __builtin_bit_cast(bf16x8, wlo[2 * ks]);
    const bf16x8 bl1 = __builtin_bit_cast(bf16x8, wlo[2 * ks + 1]);
#pragma unroll
    for (int m = 0; m < 2; ++m) {
      bf16x8 ah, al;
      if constexpr (XF) {
        split8(axp[m] + (ks << 5), ah, al);
      } else {
        ah = __builtin_bit_cast(bf16x8, *(const uint4*)(ahp[m] + (ks << 5)));
        al = __builtin_bit_cast(bf16x8, *(const uint4*)(alp[m] + (ks << 5)));
      }
      acc[m][0] = __builtin_amdgcn_mfma_f32_16x16x32_bf16(ah, bh0, acc[m][0], 0, 0, 0);
      acc[m][1] = __builtin_amdgcn_mfma_f32_16x16x32_bf16(ah, bh1, acc[m][1], 0, 0, 0);
      acc[m][0] = __builtin_amdgcn_mfma_f32_16x16x32_bf16(al, bh0, acc[m][0], 0, 0, 0);
      acc[m][1] = __builtin_amdgcn_mfma_f32_16x16x32_bf16(al, bh1, acc[m][1], 0, 0, 0);
      acc[m][0] = __builtin_amdgcn_mfma_f32_16x16x32_bf16(ah, bl0, acc[m][0], 0, 0, 0);
      acc[m][1] = __builtin_amdgcn_mfma_f32_16x16x32_bf16(ah, bl1, acc[m][1], 0, 0, 0);
    }
  }
}

// Persistent LSTM. WG w: layer=w>>7, owns 8 hidden units (all 4 gates = 32 cols).
// 512 threads = 8 waves: wave (kw = tid>>7, mh = (tid>>6)&1): K-slice x M-half.
// Phase p: layer0 does t=p, layer1 does t=p-1; one grid barrier per phase.
template <bool XCONV>
__global__ __launch_bounds__(TPB, 2) void lstm_main(
    const float* __restrict__ x,
    const unsigned short* __restrict__ xhi,
    const unsigned short* __restrict__ xlo,
    const float* __restrict__ Wih_f,
    const float* __restrict__ Whh_f,
    const float* __restrict__ bias,
    unsigned short* h0hi, unsigned short* h0lo,
    unsigned short* h1hi, unsigned short* h1lo,
    float* __restrict__ out,
    unsigned* flags, unsigned* go) {
  __shared__ char smem[LDS_BYTES];
  float* red = (float*)(smem + LDS_RED_OFF);

  const int w = blockIdx.x;
  const int tid = threadIdx.x;
  const int layer = w >> 7;
  const int j0 = (w & 127) << 3;
  const int lane = tid & 63;
  const int kw = tid >> 7;            // 0..3 K-slice
  const int mh = (tid >> 6) & 1;      // M-half
  const int mbase = mh << 5;          // row base 0 / 32
  const int cl = lane & 15;
  const int rg = lane >> 4;
  const int kfrag = rg << 3;
  const int kbase = kw << 9;
  const int krel = (kw & 1) << 9;
  const unsigned sw = (unsigned)((cl & 7) << 4);
  const unsigned bx = ((unsigned)cl << 12) + ((unsigned)(kbase + kfrag) << 1);  // unswizzled

  // ---- prologue 1: stage W_hi (bf16 of fp32 W) into LDS, XOR-swizzled
  {
    const int c = tid >> 4, sub = tid & 15;
    const int grow = ((c >> 3) << 10) + j0 + (c & 7);
    const float* s0 = Wih_f + ((size_t)layer << 22) + (size_t)grow * HD;
    const float* s1 = Whh_f + ((size_t)layer << 22) + (size_t)grow * HD;
    const unsigned cbase = (unsigned)c << 12;
    const unsigned cx = (unsigned)((c & 7) << 4);
    for (int kk = sub * 128; kk < sub * 128 + 128; kk += 8) {
      const float* sp = (kk < HD) ? (s0 + kk) : (s1 + (kk - HD));
      const float4 f0 = *(const float4*)sp;
      const float4 f1 = *(const float4*)(sp + 4);
      union { unsigned short s[8]; uint4 v; } u;
      u.s[0] = f2bf(f0.x); u.s[1] = f2bf(f0.y); u.s[2] = f2bf(f0.z); u.s[3] = f2bf(f0.w);
      u.s[4] = f2bf(f1.x); u.s[5] = f2bf(f1.y); u.s[6] = f2bf(f1.z); u.s[7] = f2bf(f1.w);
      *(uint4*)(smem + ((cbase + ((unsigned)kk << 1)) ^ cx)) = u.v;
    }
  }

  // ---- prologue 2: build this lane's W_lo B-fragments directly from fp32 W
  uint4 wlo[32];
  {
#pragma unroll
    for (int i = 0; i < 32; ++i) {
      const int nt = i & 1, ks = i >> 1;
      const int c = nt * 16 + cl;
      const int grow = ((c >> 3) << 10) + j0 + (c & 7);
      const int kglob = kbase + (ks << 5) + kfrag;
      const float* src = (kglob < HD)
          ? (Wih_f + (((size_t)layer << 22) + ((size_t)grow << 10) + kglob))
          : (Whh_f + (((size_t)layer << 22) + ((size_t)grow << 10) + (kglob - HD)));
      union { unsigned short s[8]; uint4 v; } u;
#pragma unroll
      for (int e = 0; e < 8; ++e) {
        const float vv = src[e];
        const unsigned short hb = f2bf(vv);
        u.s[e] = f2bf(vv - bf2f(hb));
      }
      wlo[i] = u.v;
    }
  }

  const int u_ = cl & 7;
  const float bi  = bias[(layer << 12) + j0 + u_];
  const float bf_ = bias[(layer << 12) + 1024 + j0 + u_];
  const float bg  = bias[(layer << 12) + 2048 + j0 + u_];
  const float bo  = bias[(layer << 12) + 3072 + j0 + u_];

  float creg[8];
#pragma unroll
  for (int i = 0; i < 8; ++i) creg[i] = 0.f;

  __syncthreads();

  for (int p = 0; p <= SEQ; ++p) {
    const bool active = layer ? (p >= 1) : (p < SEQ);
    if (active) {
      const int t = layer ? (p - 1) : p;

      f32x4 acc[2][2];
#pragma unroll
      for (int m = 0; m < 2; ++m) {
        acc[m][0] = (f32x4){0.f, 0.f, 0.f, 0.f};
        acc[m][1] = (f32x4){0.f, 0.f, 0.f, 0.f};
      }

      if (layer == 0) {
        if (kw < 2) {
          if constexpr (XCONV)
            gemm_kloop<false>(smem, nullptr, xhi + ((size_t)t << 16), xlo + ((size_t)t << 16),
                              bx, sw, krel, cl, kfrag, mbase, wlo, acc);
          else
            gemm_kloop<true>(smem, x + (size_t)t * HD, nullptr, nullptr,
                             bx, sw, krel, cl, kfrag, mbase, wlo, acc);
        } else {
          const int par = (t + 1) & 1;
          gemm_kloop<false>(smem, nullptr, h0hi + (par << 16), h0lo + (par << 16),
                            bx, sw, krel, cl, kfrag, mbase, wlo, acc);
        }
      } else {
        if (kw < 2) {
          const int par = t & 1;
          gemm_kloop<false>(smem, nullptr, h0hi + (par << 16), h0lo + (par << 16),
                            bx, sw, krel, cl, kfrag, mbase, wlo, acc);
        } else {
          const int par = (t + 1) & 1;
          gemm_kloop<false>(smem, nullptr, h1hi + (par << 16), h1lo + (par << 16),
                            bx, sw, krel, cl, kfrag, mbase, wlo, acc);
        }
      }

      // ---- cross-wave K-reduction (per M-half: waves kw>=1 dump, kw==0 combines)
      __syncthreads();
      if (kw >= 1) {
        float* rp = red + (((mh * 3 + (kw - 1)) << 10) + lane);
#pragma unroll
        for (int m = 0; m < 2; ++m)
#pragma unroll
          for (int nt = 0; nt < 2; ++nt)
#pragma unroll
            for (int r = 0; r < 4; ++r)
              rp[((m << 3) + (nt << 2) + r) << 6] = acc[m][nt][r];
      }
      __syncthreads();
      if (kw == 0) {
#pragma unroll
        for (int m = 0; m < 2; ++m)
#pragma unroll
          for (int nt = 0; nt < 2; ++nt)
#pragma unroll
            for (int r = 0; r < 4; ++r) {
              const int idx = ((m << 3) + (nt << 2) + r) << 6;
#pragma unroll
              for (int j = 0; j < 3; ++j)
                acc[m][nt][r] += red[((mh * 3 + j) << 10) + idx + lane];
            }
        // ---- pointwise (lanes cl and cl^8 duplicate consistently)
        unsigned short* hhi_d = (layer ? h1hi : h0hi) + ((t & 1) << 16);
        unsigned short* hlo_d = (layer ? h1lo : h0lo) + ((t & 1) << 16);
#pragma unroll
        for (int m = 0; m < 2; ++m) {
#pragma unroll
          for (int r = 0; r < 4; ++r) {
            const float a0 = acc[m][0][r], a1 = acc[m][1][r];
            const float a0x = __shfl_xor(a0, 8);
            const float a1x = __shfl_xor(a1, 8);
            const bool lo = (cl < 8);
            const float vi = (lo ? a0 : a0x) + bi;
            const float vf = (lo ? a0x : a0) + bf_;
            const float vg = (lo ? a1 : a1x) + bg;
            const float vo = (lo ? a1x : a1) + bo;
            const float ig = sigm(vi), fg = sigm(vf), gg = tanh_(vg), og = sigm(vo);
            const int ci = (m << 2) + r;
            const float cn = fg * creg[ci] + ig * gg;
            creg[ci] = cn;
            const float h = og * tanh_(cn);
            if (lo) {
              const int b = ((mh * 2 + m) << 4) + (rg << 2) + r;
              const int hidx = (b << 10) + j0 + u_;
              const unsigned short hb = f2bf(h);
              hhi_d[hidx] = hb;
              hlo_d[hidx] = f2bf(h - bf2f(hb));
              if (layer) {
                out[((size_t)b * SEQ + t) * HD + j0 + u_] = h;
                if (t == SEQ - 1) {
                  out[OUT_H + (size_t)(b << 10) + j0 + u_] = h;
                  out[OUT_C + (size_t)(b << 10) + j0 + u_] = cn;
                }
              }
            }
          }
        }
      }
    }
    if (p != SEQ) grid_barrier_flags(flags, go, w, (unsigned)(p + 1));
  }
}

// prep: combined bias, zero h bufs + barrier flags (every launch -- ws poisoned)
__global__ void lstm_prep(const float* __restrict__ bih, const float* __restrict__ bhh,
                          float* __restrict__ bias,
                          unsigned short* __restrict__ h0hi, unsigned short* __restrict__ h0lo,
                          unsigned short* __restrict__ h1hi, unsigned short* __restrict__ h1lo,
                          unsigned* __restrict__ bar) {
  const size_t i0 = (size_t)blockIdx.x * blockDim.x + threadIdx.x;
  const size_t stride = (size_t)gridDim.x * blockDim.x;
  for (size_t idx = i0; idx < 8192; idx += stride) bias[idx] = bih[idx] + bhh[idx];
  const ushort4 z = make_ushort4(0, 0, 0, 0);
  for (size_t idx = i0; idx < 32768; idx += stride) {
    ((ushort4*)h0hi)[idx] = z; ((ushort4*)h0lo)[idx] = z;
    ((ushort4*)h1hi)[idx] = z; ((ushort4*)h1lo)[idx] = z;
  }
  for (size_t idx = i0; idx < 8256; idx += stride) bar[idx] = 0u;  // flags + go line
}

// convert x[b][t][k] fp32 -> t-major bf16 hi/lo panels xhi/xlo[((t*64+b)<<10)+k]
__global__ void x_convert(const float* __restrict__ x,
                          unsigned short* __restrict__ xhi,
                          unsigned short* __restrict__ xlo) {
  const size_t tidg = (size_t)blockIdx.x * blockDim.x + threadIdx.x;
  const int k8 = (int)(tidg & 127);
  const size_t bt = tidg >> 7;
  const int b = (int)(bt >> 9);
  const int t = (int)(bt & 511);
  const float* src = x + (((size_t)b * SEQ + t) << 10) + (k8 << 3);
  const size_t dst = (((size_t)t * 64 + b) << 10) + (k8 << 3);
  const float4 f0 = *(const float4*)src;
  const float4 f1 = *(const float4*)(src + 4);
  union { unsigned short s[8]; uint4 v; } uh, ul;
  const float e[8] = {f0.x, f0.y, f0.z, f0.w, f1.x, f1.y, f1.z, f1.w};
#pragma unroll
  for (int i = 0; i < 8; ++i) {
    const unsigned short hb = f2bf(e[i]);
    uh.s[i] = hb;
    ul.s[i] = f2bf(e[i] - bf2f(hb));
  }
  *(uint4*)(xhi + dst) = uh.v;
  *(uint4*)(xlo + dst) = ul.v;
}

extern "C" void kernel_launch(void* const* d_in, const int* in_sizes, int n_in,
                              void* d_out, int out_size, void* d_ws, size_t ws_size,
                              hipStream_t stream) {
  const float* x     = (const float*)d_in[0];
  const float* Wih_f = (const float*)d_in[1];
  const float* bih   = (const float*)d_in[2];
  const float* Whh_f = (const float*)d_in[3];
  const float* bhh   = (const float*)d_in[4];
  float* out = (float*)d_out;

  char* ws = (char*)d_ws;
  float* bias           = (float*)(ws);                       // 32 KB
  unsigned short* h0hi  = (unsigned short*)(ws + 32768);      // 256 KB each (2 parities)
  unsigned short* h0lo  = (unsigned short*)(ws + 32768 + 262144);
  unsigned short* h1hi  = (unsigned short*)(ws + 32768 + 2 * 262144);
  unsigned short* h1lo  = (unsigned short*)(ws + 32768 + 3 * 262144);
  unsigned* bar         = (unsigned*)(ws + 32768 + 4 * 262144);  // 32KB flags + go
  unsigned* flags       = bar;
  unsigned* go          = bar + 8192;
  unsigned short* xhi   = (unsigned short*)(ws + (2ull << 20));
  unsigned short* xlo   = (unsigned short*)(ws + (2ull << 20) + (64ull << 20));

  const bool xc = ws_size >= (2ull << 20) + (128ull << 20) + (1ull << 20);

  hipLaunchKernelGGL(lstm_prep, dim3(256), dim3(256), 0, stream,
                     bih, bhh, bias, h0hi, h0lo, h1hi, h1lo, bar);

  if (xc) {
    hipLaunchKernelGGL(x_convert, dim3(16384), dim3(256), 0, stream, x, xhi, xlo);
    hipLaunchKernelGGL(lstm_main<true>, dim3(NWG), dim3(TPB), 0, stream,
                       x, xhi, xlo, Wih_f, Whh_f, bias, h0hi, h0lo, h1hi, h1lo, out, flags, go);
  } else {
    hipLaunchKernelGGL(lstm_main<false>, dim3(NWG), dim3(TPB), 0, stream,
                       x, xhi, xlo, Wih_f, Whh_f, bias, h0hi, h0lo, h1hi, h1lo, out, flags, go);
  }
}

// Round 7
// 11204.983 us; speedup vs baseline: 3.5463x; 1.2112x over previous
//
#include <hip/hip_runtime.h>
#include <hip/hip_bf16.h>

#define SEQ 512
#define HD 1024
#define NWG 256
#define TPB 256
#define LDS_RED_OFF 131072
#define LDS_BYTES (131072 + 24576)
#define OUT_H 33554432ull
#define OUT_C 33619968ull

typedef __bf16 bf16x8 __attribute__((ext_vector_type(8)));
typedef float f32x4 __attribute__((ext_vector_type(4)));

__device__ __forceinline__ unsigned short f2bf(float f) {
  __hip_bfloat16 b = __float2bfloat16(f);  // RNE
  return __builtin_bit_cast(unsigned short, b);
}
__device__ __forceinline__ float bf2f(unsigned short s) {
  return __builtin_bit_cast(float, (unsigned)s << 16);  // exact widen
}

__device__ __forceinline__ float sigm(float v) { return 1.f / (1.f + __expf(-v)); }
__device__ __forceinline__ float tanh_(float v) {
  float av = fabsf(v);
  float e = __expf(-2.f * av);
  float t = (1.f - e) / (1.f + e);
  return copysignf(t, v);
}

// async global->LDS, 16B per lane; LDS dest = wave-uniform base + lane*16
__device__ __forceinline__ void gl2lds(const void* g, void* l) {
  __builtin_amdgcn_global_load_lds(
      (const __attribute__((address_space(1))) void*)g,
      (__attribute__((address_space(3))) void*)l, 16, 0, 0);
}

// Flag-array grid barrier with acquire hoisted into the wait window (round-5 fix).
__device__ __forceinline__ void grid_barrier_flags(unsigned* flags, unsigned* go,
                                                   int w, unsigned e) {
  __syncthreads();
  if (w == 0) {
    const int i = threadIdx.x;
    if (i == 0) {
      __builtin_amdgcn_fence(__ATOMIC_RELEASE, "agent");
      __builtin_amdgcn_fence(__ATOMIC_ACQUIRE, "agent");
    }
    if (i > 0 && i < 256) {
      while (__hip_atomic_load(flags + i * 32, __ATOMIC_RELAXED, __HIP_MEMORY_SCOPE_AGENT) < e)
        __builtin_amdgcn_s_sleep(1);
    }
    __syncthreads();
    if (i == 0)
      __hip_atomic_store(go, e, __ATOMIC_RELAXED, __HIP_MEMORY_SCOPE_AGENT);
  } else {
    if (threadIdx.x == 0) {
      __builtin_amdgcn_fence(__ATOMIC_RELEASE, "agent");
      __hip_atomic_store(flags + w * 32, e, __ATOMIC_RELAXED, __HIP_MEMORY_SCOPE_AGENT);
      __builtin_amdgcn_fence(__ATOMIC_ACQUIRE, "agent");
      while (__hip_atomic_load(go, __ATOMIC_RELAXED, __HIP_MEMORY_SCOPE_AGENT) < e)
        __builtin_amdgcn_s_sleep(1);
    }
  }
  __syncthreads();
}

// Persistent LSTM, round-7 structure:
//  - W (hi AND lo) fully in registers per wave (256 regs of uint4 fragments)
//  - A-panels staged into LDS via global_load_lds, double-buffered 2x64KB,
//    per-wave 16KB stripes, K-64 steps, vmcnt(16) pipelining, zero kloop syncs
//  - source-pre-swizzled staging so linear LDS dest == swizzled layout (m173)
//  - reduction + pointwise + flag barrier identical to round 5 (bit-identical math)
__global__ __launch_bounds__(TPB, 1) void lstm_main(
    const float* __restrict__ x,
    const float* __restrict__ Wih_f,
    const float* __restrict__ Whh_f,
    const float* __restrict__ bias,
    unsigned short* h0hi, unsigned short* h0lo,
    unsigned short* h1hi, unsigned short* h1lo,
    float* __restrict__ out,
    unsigned* flags, unsigned* go) {
  __shared__ char smem[LDS_BYTES];
  float* red = (float*)(smem + LDS_RED_OFF);

  const int w = blockIdx.x;
  const int tid = threadIdx.x;
  const int layer = w >> 7;
  const int j0 = (w & 127) << 3;
  const int lane = tid & 63;
  const int kw = tid >> 6;
  const int cl = lane & 15;
  const int rg = lane >> 4;
  const int kbase = kw << 9;
  const int krel = (kw & 1) << 9;
  const bool isx = (layer == 0) && (kw < 2);

  // ---- W prologue: build hi+lo B-fragments in registers from fp32 W
  uint4 whi[32], wlo[32];
#pragma unroll
  for (int i = 0; i < 32; ++i) {
    const int nt = i & 1, ks = i >> 1;
    const int c = nt * 16 + cl;
    const int grow = ((c >> 3) << 10) + j0 + (c & 7);
    const int kglob = kbase + (ks << 5) + (rg << 3);
    const float* src = (kglob < HD)
        ? (Wih_f + (((size_t)layer << 22) + ((size_t)grow << 10) + kglob))
        : (Whh_f + (((size_t)layer << 22) + ((size_t)grow << 10) + (kglob - HD)));
    union { unsigned short s2[8]; uint4 v; } uh, ul;
#pragma unroll
    for (int e = 0; e < 8; ++e) {
      const float vv = src[e];
      const unsigned short hb = f2bf(vv);
      uh.s2[e] = hb;
      ul.s2[e] = f2bf(vv - bf2f(hb));
    }
    whi[i] = uh.v;
    wlo[i] = ul.v;
  }

  const int u_ = cl & 7;
  const float bi  = bias[(layer << 12) + j0 + u_];
  const float bf_ = bias[(layer << 12) + 1024 + j0 + u_];
  const float bg  = bias[(layer << 12) + 2048 + j0 + u_];
  const float bo  = bias[(layer << 12) + 3072 + j0 + u_];

  float creg[16];
#pragma unroll
  for (int i = 0; i < 16; ++i) creg[i] = 0.f;

  // staging lane constants
  char* stripe = smem + (kw << 14);   // buf0 stripe; buf1 = +65536
  // h-type: issue i covers rows i*8 + (lane>>3); (row&7) == lane>>3 always
  const int hrr = lane >> 3;
  const int hjj = lane & 7;
  const int hsw = hjj ^ hrr;          // pre-swizzled source slot (8 elems each)
  // x-type: issue i covers rows i*4 + (lane>>4); (row&7) = 4*(i&1) + (lane>>4)
  const int xrr = lane >> 4;
  const int xjj = lane & 15;
  const int xslotE = xjj ^ xrr;       // even issues
  const int xslotO = xjj ^ (4 + xrr); // odd issues

  __syncthreads();

  for (int p = 0; p <= SEQ; ++p) {
    const bool active = layer ? (p >= 1) : (p < SEQ);
    if (active) {
      const int t = layer ? (p - 1) : p;

      f32x4 acc[4][2];
#pragma unroll
      for (int mt = 0; mt < 4; ++mt) {
        acc[mt][0] = (f32x4){0.f, 0.f, 0.f, 0.f};
        acc[mt][1] = (f32x4){0.f, 0.f, 0.f, 0.f};
      }

      if (isx) {
        // ---- x path: stage raw fp32, split hi/lo after LDS read
        const float* pxE = x + ((size_t)(xrr * SEQ + t) << 10) + kbase + (xslotE << 2);
        const float* pxO = x + ((size_t)(xrr * SEQ + t) << 10) + kbase + (xslotO << 2);
#pragma unroll
        for (int i = 0; i < 16; ++i)
          gl2lds(((i & 1) ? pxO : pxE) + (size_t)i * 2097152, stripe + i * 1024);
#pragma unroll
        for (int s = 0; s < 8; ++s) {
          char* cb = stripe + ((s & 1) << 16);
          if (s < 7) {
            char* nb = stripe + (((s + 1) & 1) << 16);
            const int so = (s + 1) << 6;
#pragma unroll
            for (int i = 0; i < 16; ++i)
              gl2lds(((i & 1) ? pxO : pxE) + (size_t)i * 2097152 + so, nb + i * 1024);
            asm volatile("s_waitcnt vmcnt(16)" ::: "memory");
          } else {
            asm volatile("s_waitcnt vmcnt(0)" ::: "memory");
          }
#pragma unroll
          for (int ksl = 0; ksl < 2; ++ksl) {
            const int ig = (((s << 1) + ksl) << 1);
            const bf16x8 bh0 = __builtin_bit_cast(bf16x8, whi[ig]);
            const bf16x8 bh1 = __builtin_bit_cast(bf16x8, whi[ig + 1]);
            const bf16x8 bl0 = __builtin_bit_cast(bf16x8, wlo[ig]);
            const bf16x8 bl1 = __builtin_bit_cast(bf16x8, wlo[ig + 1]);
#pragma unroll
            for (int mt = 0; mt < 4; ++mt) {
              const int r = (mt << 4) + cl;
              const int a0 = (ksl << 3) + (rg << 1);
              const float4 f0 = *(const float4*)(cb + r * 256 + ((a0 ^ (cl & 7)) << 4));
              const float4 f1 = *(const float4*)(cb + r * 256 + (((a0 + 1) ^ (cl & 7)) << 4));
              union { unsigned short s2[8]; uint4 v; } uh, ul;
              const float ee[8] = {f0.x, f0.y, f0.z, f0.w, f1.x, f1.y, f1.z, f1.w};
#pragma unroll
              for (int e = 0; e < 8; ++e) {
                const unsigned short hb = f2bf(ee[e]);
                uh.s2[e] = hb;
                ul.s2[e] = f2bf(ee[e] - bf2f(hb));
              }
              const bf16x8 ah = __builtin_bit_cast(bf16x8, uh.v);
              const bf16x8 al = __builtin_bit_cast(bf16x8, ul.v);
              acc[mt][0] = __builtin_amdgcn_mfma_f32_16x16x32_bf16(ah, bh0, acc[mt][0], 0, 0, 0);
              acc[mt][1] = __builtin_amdgcn_mfma_f32_16x16x32_bf16(ah, bh1, acc[mt][1], 0, 0, 0);
              acc[mt][0] = __builtin_amdgcn_mfma_f32_16x16x32_bf16(al, bh0, acc[mt][0], 0, 0, 0);
              acc[mt][1] = __builtin_amdgcn_mfma_f32_16x16x32_bf16(al, bh1, acc[mt][1], 0, 0, 0);
              acc[mt][0] = __builtin_amdgcn_mfma_f32_16x16x32_bf16(ah, bl0, acc[mt][0], 0, 0, 0);
              acc[mt][1] = __builtin_amdgcn_mfma_f32_16x16x32_bf16(ah, bl1, acc[mt][1], 0, 0, 0);
            }
          }
        }
      } else {
        // ---- h path: stage bf16 hi+lo stripes
        const unsigned short *shi_, *slo_;
        if (layer == 0) {
          const int par = (t + 1) & 1;
          shi_ = h0hi + (par << 16); slo_ = h0lo + (par << 16);
        } else if (kw < 2) {
          const int par = t & 1;
          shi_ = h0hi + (par << 16); slo_ = h0lo + (par << 16);
        } else {
          const int par = (t + 1) & 1;
          shi_ = h1hi + (par << 16); slo_ = h1lo + (par << 16);
        }
        const unsigned short* ph = shi_ + (hrr << 10) + krel + (hsw << 3);
        const unsigned short* pl = slo_ + (hrr << 10) + krel + (hsw << 3);
#pragma unroll
        for (int i = 0; i < 8; ++i) {
          gl2lds(ph + i * 8192, stripe + i * 1024);
          gl2lds(pl + i * 8192, stripe + 8192 + i * 1024);
        }
#pragma unroll
        for (int s = 0; s < 8; ++s) {
          char* cb = stripe + ((s & 1) << 16);
          if (s < 7) {
            char* nb = stripe + (((s + 1) & 1) << 16);
            const int so = (s + 1) << 6;
#pragma unroll
            for (int i = 0; i < 8; ++i) {
              gl2lds(ph + so + i * 8192, nb + i * 1024);
              gl2lds(pl + so + i * 8192, nb + 8192 + i * 1024);
            }
            asm volatile("s_waitcnt vmcnt(16)" ::: "memory");
          } else {
            asm volatile("s_waitcnt vmcnt(0)" ::: "memory");
          }
#pragma unroll
          for (int ksl = 0; ksl < 2; ++ksl) {
            const int ig = (((s << 1) + ksl) << 1);
            const bf16x8 bh0 = __builtin_bit_cast(bf16x8, whi[ig]);
            const bf16x8 bh1 = __builtin_bit_cast(bf16x8, whi[ig + 1]);
            const bf16x8 bl0 = __builtin_bit_cast(bf16x8, wlo[ig]);
            const bf16x8 bl1 = __builtin_bit_cast(bf16x8, wlo[ig + 1]);
#pragma unroll
            for (int mt = 0; mt < 4; ++mt) {
              const int r = (mt << 4) + cl;
              const unsigned off = (unsigned)(r << 7) +
                  (unsigned)(((((ksl << 2) + rg)) ^ (cl & 7)) << 4);
              const bf16x8 ah = __builtin_bit_cast(bf16x8, *(const uint4*)(cb + off));
              const bf16x8 al = __builtin_bit_cast(bf16x8, *(const uint4*)(cb + 8192 + off));
              acc[mt][0] = __builtin_amdgcn_mfma_f32_16x16x32_bf16(ah, bh0, acc[mt][0], 0, 0, 0);
              acc[mt][1] = __builtin_amdgcn_mfma_f32_16x16x32_bf16(ah, bh1, acc[mt][1], 0, 0, 0);
              acc[mt][0] = __builtin_amdgcn_mfma_f32_16x16x32_bf16(al, bh0, acc[mt][0], 0, 0, 0);
              acc[mt][1] = __builtin_amdgcn_mfma_f32_16x16x32_bf16(al, bh1, acc[mt][1], 0, 0, 0);
              acc[mt][0] = __builtin_amdgcn_mfma_f32_16x16x32_bf16(ah, bl0, acc[mt][0], 0, 0, 0);
              acc[mt][1] = __builtin_amdgcn_mfma_f32_16x16x32_bf16(ah, bl1, acc[mt][1], 0, 0, 0);
            }
          }
        }
      }

      // ---- cross-wave K-reduction (round-5 verbatim)
      if (kw >= 1) {
        float* rp = red + (((kw - 1) << 11) + lane);
#pragma unroll
        for (int mt = 0; mt < 4; ++mt)
#pragma unroll
          for (int nt = 0; nt < 2; ++nt)
#pragma unroll
            for (int r = 0; r < 4; ++r)
              rp[((mt << 3) + (nt << 2) + r) << 6] = acc[mt][nt][r];
      }
      __syncthreads();
      if (kw == 0) {
#pragma unroll
        for (int mt = 0; mt < 4; ++mt)
#pragma unroll
          for (int nt = 0; nt < 2; ++nt)
#pragma unroll
            for (int r = 0; r < 4; ++r) {
              const int idx = ((mt << 3) + (nt << 2) + r) << 6;
              acc[mt][nt][r] += red[idx + lane] + red[2048 + idx + lane] + red[4096 + idx + lane];
            }
        // ---- pointwise (round-5 verbatim)
        unsigned short* hhi_d = (layer ? h1hi : h0hi) + ((t & 1) << 16);
        unsigned short* hlo_d = (layer ? h1lo : h0lo) + ((t & 1) << 16);
#pragma unroll
        for (int mt = 0; mt < 4; ++mt) {
#pragma unroll
          for (int r = 0; r < 4; ++r) {
            const float a0 = acc[mt][0][r], a1 = acc[mt][1][r];
            const float a0x = __shfl_xor(a0, 8);
            const float a1x = __shfl_xor(a1, 8);
            const bool lo = (cl < 8);
            const float vi = (lo ? a0 : a0x) + bi;
            const float vf = (lo ? a0x : a0) + bf_;
            const float vg = (lo ? a1 : a1x) + bg;
            const float vo = (lo ? a1x : a1) + bo;
            const float ig = sigm(vi), fg = sigm(vf), gg = tanh_(vg), og = sigm(vo);
            const int ci = (mt << 2) + r;
            const float cn = fg * creg[ci] + ig * gg;
            creg[ci] = cn;
            const float h = og * tanh_(cn);
            if (lo) {
              const int b = (mt << 4) + (rg << 2) + r;
              const int hidx = (b << 10) + j0 + u_;
              const unsigned short hb = f2bf(h);
              hhi_d[hidx] = hb;
              hlo_d[hidx] = f2bf(h - bf2f(hb));
              if (layer) {
                out[((size_t)b * SEQ + t) * HD + j0 + u_] = h;
                if (t == SEQ - 1) {
                  out[OUT_H + (size_t)(b << 10) + j0 + u_] = h;
                  out[OUT_C + (size_t)(b << 10) + j0 + u_] = cn;
                }
              }
            }
          }
        }
      }
    }
    if (p != SEQ) grid_barrier_flags(flags, go, w, (unsigned)(p + 1));
  }
}

// prep: combined bias, zero h bufs + barrier flags (every launch -- ws poisoned)
__global__ void lstm_prep(const float* __restrict__ bih, const float* __restrict__ bhh,
                          float* __restrict__ bias,
                          unsigned short* __restrict__ h0hi, unsigned short* __restrict__ h0lo,
                          unsigned short* __restrict__ h1hi, unsigned short* __restrict__ h1lo,
                          unsigned* __restrict__ bar) {
  const size_t i0 = (size_t)blockIdx.x * blockDim.x + threadIdx.x;
  const size_t stride = (size_t)gridDim.x * blockDim.x;
  for (size_t idx = i0; idx < 8192; idx += stride) bias[idx] = bih[idx] + bhh[idx];
  const ushort4 z = make_ushort4(0, 0, 0, 0);
  for (size_t idx = i0; idx < 32768; idx += stride) {
    ((ushort4*)h0hi)[idx] = z; ((ushort4*)h0lo)[idx] = z;
    ((ushort4*)h1hi)[idx] = z; ((ushort4*)h1lo)[idx] = z;
  }
  for (size_t idx = i0; idx < 8256; idx += stride) bar[idx] = 0u;  // flags + go line
}

extern "C" void kernel_launch(void* const* d_in, const int* in_sizes, int n_in,
                              void* d_out, int out_size, void* d_ws, size_t ws_size,
                              hipStream_t stream) {
  const float* x     = (const float*)d_in[0];
  const float* Wih_f = (const float*)d_in[1];
  const float* bih   = (const float*)d_in[2];
  const float* Whh_f = (const float*)d_in[3];
  const float* bhh   = (const float*)d_in[4];
  float* out = (float*)d_out;

  char* ws = (char*)d_ws;
  float* bias           = (float*)(ws);                       // 32 KB
  unsigned short* h0hi  = (unsigned short*)(ws + 32768);      // 256 KB each (2 parities)
  unsigned short* h0lo  = (unsigned short*)(ws + 32768 + 262144);
  unsigned short* h1hi  = (unsigned short*)(ws + 32768 + 2 * 262144);
  unsigned short* h1lo  = (unsigned short*)(ws + 32768 + 3 * 262144);
  unsigned* bar         = (unsigned*)(ws + 32768 + 4 * 262144);  // flags + go
  unsigned* flags       = bar;
  unsigned* go          = bar + 8192;

  hipLaunchKernelGGL(lstm_prep, dim3(256), dim3(256), 0, stream,
                     bih, bhh, bias, h0hi, h0lo, h1hi, h1lo, bar);

  hipLaunchKernelGGL(lstm_main, dim3(NWG), dim3(TPB), 0, stream,
                     x, Wih_f, Whh_f, bias, h0hi, h0lo, h1hi, h1lo, out, flags, go);
}

// Round 8
// 10013.657 us; speedup vs baseline: 3.9682x; 1.1190x over previous
//
#include <hip/hip_runtime.h>
#include <hip/hip_bf16.h>

#define SEQ 512
#define HD 1024
#define NWG 256
#define TPB 256
#define LDS_RED_OFF 131072
#define LDS_BYTES (131072 + 24576)
#define OUT_H 33554432ull
#define OUT_C 33619968ull
#define RMASK 31   // 32-slot h ring; inv cadence 16 covers slot reuse

typedef __bf16 bf16x8 __attribute__((ext_vector_type(8)));
typedef float f32x4 __attribute__((ext_vector_type(4)));

__device__ __forceinline__ unsigned short f2bf(float f) {
  __hip_bfloat16 b = __float2bfloat16(f);  // RNE
  return __builtin_bit_cast(unsigned short, b);
}
__device__ __forceinline__ float bf2f(unsigned short s) {
  return __builtin_bit_cast(float, (unsigned)s << 16);  // exact widen
}

__device__ __forceinline__ float sigm(float v) { return 1.f / (1.f + __expf(-v)); }
__device__ __forceinline__ float tanh_(float v) {
  float av = fabsf(v);
  float e = __expf(-2.f * av);
  float t = (1.f - e) / (1.f + e);
  return copysignf(t, v);
}

// async global->LDS (cached, aux=0), 16B/lane; LDS dest = wave base + lane*16
__device__ __forceinline__ void gl2lds(const void* g, void* l) {
  __builtin_amdgcn_global_load_lds(
      (const __attribute__((address_space(1))) void*)g,
      (__attribute__((address_space(3))) void*)l, 16, 0, 0);
}

// Fence-free flag barrier (round-8): h is published via agent-scope relaxed
// stores (write-through to L3), drained with vmcnt(0) before the arrival flag.
// No wbl2 ever; buffer_inv only on flush phases (every 16) to cover h-ring
// slot reuse (32 slots, 2 invs per reuse window) -> L2 stays hot all phase.
__device__ __forceinline__ void grid_barrier_flags(unsigned* flags, unsigned* go,
                                                   int w, unsigned e, bool flush) {
  __syncthreads();
  if (w == 0) {
    const int i = threadIdx.x;
    if (i == 0) asm volatile("s_waitcnt vmcnt(0)" ::: "memory");
    if (i > 0 && i < 256) {
      while (__hip_atomic_load(flags + i * 32, __ATOMIC_RELAXED, __HIP_MEMORY_SCOPE_AGENT) < e)
        __builtin_amdgcn_s_sleep(1);
    }
    __syncthreads();
    if (i == 0) {
      __hip_atomic_store(go, e, __ATOMIC_RELAXED, __HIP_MEMORY_SCOPE_AGENT);
      if (flush) __builtin_amdgcn_fence(__ATOMIC_ACQUIRE, "agent");
    }
  } else {
    if (threadIdx.x == 0) {
      asm volatile("s_waitcnt vmcnt(0)" ::: "memory");
      __hip_atomic_store(flags + w * 32, e, __ATOMIC_RELAXED, __HIP_MEMORY_SCOPE_AGENT);
      while (__hip_atomic_load(go, __ATOMIC_RELAXED, __HIP_MEMORY_SCOPE_AGENT) < e)
        __builtin_amdgcn_s_sleep(1);
      if (flush) __builtin_amdgcn_fence(__ATOMIC_ACQUIRE, "agent");
    }
  }
  __syncthreads();
}

// Persistent LSTM, round-8 structure:
//  - W (hi+lo) in registers; A staged via gl2lds double-buffer (round-7)
//  - h ring of 32 slots; h stores = relaxed agent atomics (no fences)
//  - grid barrier = pure flag exchange; inv every 16 phases only
__global__ __launch_bounds__(TPB, 1) void lstm_main(
    const float* __restrict__ x,
    const float* __restrict__ Wih_f,
    const float* __restrict__ Whh_f,
    const float* __restrict__ bias,
    unsigned short* h0hi, unsigned short* h0lo,
    unsigned short* h1hi, unsigned short* h1lo,
    float* __restrict__ out,
    unsigned* flags, unsigned* go) {
  __shared__ char smem[LDS_BYTES];
  float* red = (float*)(smem + LDS_RED_OFF);

  const int w = blockIdx.x;
  const int tid = threadIdx.x;
  const int layer = w >> 7;
  const int j0 = (w & 127) << 3;
  const int lane = tid & 63;
  const int kw = tid >> 6;
  const int cl = lane & 15;
  const int rg = lane >> 4;
  const int kbase = kw << 9;
  const int krel = (kw & 1) << 9;
  const bool isx = (layer == 0) && (kw < 2);

  // ---- W prologue: build hi+lo B-fragments in registers from fp32 W
  uint4 whi[32], wlo[32];
#pragma unroll
  for (int i = 0; i < 32; ++i) {
    const int nt = i & 1, ks = i >> 1;
    const int c = nt * 16 + cl;
    const int grow = ((c >> 3) << 10) + j0 + (c & 7);
    const int kglob = kbase + (ks << 5) + (rg << 3);
    const float* src = (kglob < HD)
        ? (Wih_f + (((size_t)layer << 22) + ((size_t)grow << 10) + kglob))
        : (Whh_f + (((size_t)layer << 22) + ((size_t)grow << 10) + (kglob - HD)));
    union { unsigned short s2[8]; uint4 v; } uh, ul;
#pragma unroll
    for (int e = 0; e < 8; ++e) {
      const float vv = src[e];
      const unsigned short hb = f2bf(vv);
      uh.s2[e] = hb;
      ul.s2[e] = f2bf(vv - bf2f(hb));
    }
    whi[i] = uh.v;
    wlo[i] = ul.v;
  }

  const int u_ = cl & 7;
  const float bi  = bias[(layer << 12) + j0 + u_];
  const float bf_ = bias[(layer << 12) + 1024 + j0 + u_];
  const float bg  = bias[(layer << 12) + 2048 + j0 + u_];
  const float bo  = bias[(layer << 12) + 3072 + j0 + u_];

  float creg[16];
#pragma unroll
  for (int i = 0; i < 16; ++i) creg[i] = 0.f;

  // staging lane constants
  char* stripe = smem + (kw << 14);   // buf0 stripe; buf1 = +65536
  const int hrr = lane >> 3;
  const int hjj = lane & 7;
  const int hsw = hjj ^ hrr;          // pre-swizzled source slot (8 elems each)
  const int xrr = lane >> 4;
  const int xjj = lane & 15;
  const int xslotE = xjj ^ xrr;       // even issues
  const int xslotO = xjj ^ (4 + xrr); // odd issues

  __syncthreads();

  for (int p = 0; p <= SEQ; ++p) {
    const bool active = layer ? (p >= 1) : (p < SEQ);
    if (active) {
      const int t = layer ? (p - 1) : p;

      f32x4 acc[4][2];
#pragma unroll
      for (int mt = 0; mt < 4; ++mt) {
        acc[mt][0] = (f32x4){0.f, 0.f, 0.f, 0.f};
        acc[mt][1] = (f32x4){0.f, 0.f, 0.f, 0.f};
      }

      if (isx) {
        // ---- x path: stage raw fp32, split hi/lo after LDS read
        const float* pxE = x + ((size_t)(xrr * SEQ + t) << 10) + kbase + (xslotE << 2);
        const float* pxO = x + ((size_t)(xrr * SEQ + t) << 10) + kbase + (xslotO << 2);
#pragma unroll
        for (int i = 0; i < 16; ++i)
          gl2lds(((i & 1) ? pxO : pxE) + (size_t)i * 2097152, stripe + i * 1024);
#pragma unroll
        for (int s = 0; s < 8; ++s) {
          char* cb = stripe + ((s & 1) << 16);
          if (s < 7) {
            char* nb = stripe + (((s + 1) & 1) << 16);
            const int so = (s + 1) << 6;
#pragma unroll
            for (int i = 0; i < 16; ++i)
              gl2lds(((i & 1) ? pxO : pxE) + (size_t)i * 2097152 + so, nb + i * 1024);
            asm volatile("s_waitcnt vmcnt(16)" ::: "memory");
          } else {
            asm volatile("s_waitcnt vmcnt(0)" ::: "memory");
          }
#pragma unroll
          for (int ksl = 0; ksl < 2; ++ksl) {
            const int ig = (((s << 1) + ksl) << 1);
            const bf16x8 bh0 = __builtin_bit_cast(bf16x8, whi[ig]);
            const bf16x8 bh1 = __builtin_bit_cast(bf16x8, whi[ig + 1]);
            const bf16x8 bl0 = __builtin_bit_cast(bf16x8, wlo[ig]);
            const bf16x8 bl1 = __builtin_bit_cast(bf16x8, wlo[ig + 1]);
#pragma unroll
            for (int mt = 0; mt < 4; ++mt) {
              const int r = (mt << 4) + cl;
              const int a0 = (ksl << 3) + (rg << 1);
              const float4 f0 = *(const float4*)(cb + r * 256 + ((a0 ^ (cl & 7)) << 4));
              const float4 f1 = *(const float4*)(cb + r * 256 + (((a0 + 1) ^ (cl & 7)) << 4));
              union { unsigned short s2[8]; uint4 v; } uh, ul;
              const float ee[8] = {f0.x, f0.y, f0.z, f0.w, f1.x, f1.y, f1.z, f1.w};
#pragma unroll
              for (int e = 0; e < 8; ++e) {
                const unsigned short hb = f2bf(ee[e]);
                uh.s2[e] = hb;
                ul.s2[e] = f2bf(ee[e] - bf2f(hb));
              }
              const bf16x8 ah = __builtin_bit_cast(bf16x8, uh.v);
              const bf16x8 al = __builtin_bit_cast(bf16x8, ul.v);
              acc[mt][0] = __builtin_amdgcn_mfma_f32_16x16x32_bf16(ah, bh0, acc[mt][0], 0, 0, 0);
              acc[mt][1] = __builtin_amdgcn_mfma_f32_16x16x32_bf16(ah, bh1, acc[mt][1], 0, 0, 0);
              acc[mt][0] = __builtin_amdgcn_mfma_f32_16x16x32_bf16(al, bh0, acc[mt][0], 0, 0, 0);
              acc[mt][1] = __builtin_amdgcn_mfma_f32_16x16x32_bf16(al, bh1, acc[mt][1], 0, 0, 0);
              acc[mt][0] = __builtin_amdgcn_mfma_f32_16x16x32_bf16(ah, bl0, acc[mt][0], 0, 0, 0);
              acc[mt][1] = __builtin_amdgcn_mfma_f32_16x16x32_bf16(ah, bl1, acc[mt][1], 0, 0, 0);
            }
          }
        }
      } else {
        // ---- h path: stage bf16 hi+lo stripes from ring slot (cached reads)
        const unsigned short *shi_, *slo_;
        if (layer == 0) {
          const int sl = (t - 1) & RMASK;
          shi_ = h0hi + (sl << 16); slo_ = h0lo + (sl << 16);
        } else if (kw < 2) {
          const int sl = t & RMASK;
          shi_ = h0hi + (sl << 16); slo_ = h0lo + (sl << 16);
        } else {
          const int sl = (t - 1) & RMASK;
          shi_ = h1hi + (sl << 16); slo_ = h1lo + (sl << 16);
        }
        const unsigned short* ph = shi_ + (hrr << 10) + krel + (hsw << 3);
        const unsigned short* pl = slo_ + (hrr << 10) + krel + (hsw << 3);
#pragma unroll
        for (int i = 0; i < 8; ++i) {
          gl2lds(ph + i * 8192, stripe + i * 1024);
          gl2lds(pl + i * 8192, stripe + 8192 + i * 1024);
        }
#pragma unroll
        for (int s = 0; s < 8; ++s) {
          char* cb = stripe + ((s & 1) << 16);
          if (s < 7) {
            char* nb = stripe + (((s + 1) & 1) << 16);
            const int so = (s + 1) << 6;
#pragma unroll
            for (int i = 0; i < 8; ++i) {
              gl2lds(ph + so + i * 8192, nb + i * 1024);
              gl2lds(pl + so + i * 8192, nb + 8192 + i * 1024);
            }
            asm volatile("s_waitcnt vmcnt(16)" ::: "memory");
          } else {
            asm volatile("s_waitcnt vmcnt(0)" ::: "memory");
          }
#pragma unroll
          for (int ksl = 0; ksl < 2; ++ksl) {
            const int ig = (((s << 1) + ksl) << 1);
            const bf16x8 bh0 = __builtin_bit_cast(bf16x8, whi[ig]);
            const bf16x8 bh1 = __builtin_bit_cast(bf16x8, whi[ig + 1]);
            const bf16x8 bl0 = __builtin_bit_cast(bf16x8, wlo[ig]);
            const bf16x8 bl1 = __builtin_bit_cast(bf16x8, wlo[ig + 1]);
#pragma unroll
            for (int mt = 0; mt < 4; ++mt) {
              const int r = (mt << 4) + cl;
              const unsigned off = (unsigned)(r << 7) +
                  (unsigned)(((((ksl << 2) + rg)) ^ (cl & 7)) << 4);
              const bf16x8 ah = __builtin_bit_cast(bf16x8, *(const uint4*)(cb + off));
              const bf16x8 al = __builtin_bit_cast(bf16x8, *(const uint4*)(cb + 8192 + off));
              acc[mt][0] = __builtin_amdgcn_mfma_f32_16x16x32_bf16(ah, bh0, acc[mt][0], 0, 0, 0);
              acc[mt][1] = __builtin_amdgcn_mfma_f32_16x16x32_bf16(ah, bh1, acc[mt][1], 0, 0, 0);
              acc[mt][0] = __builtin_amdgcn_mfma_f32_16x16x32_bf16(al, bh0, acc[mt][0], 0, 0, 0);
              acc[mt][1] = __builtin_amdgcn_mfma_f32_16x16x32_bf16(al, bh1, acc[mt][1], 0, 0, 0);
              acc[mt][0] = __builtin_amdgcn_mfma_f32_16x16x32_bf16(ah, bl0, acc[mt][0], 0, 0, 0);
              acc[mt][1] = __builtin_amdgcn_mfma_f32_16x16x32_bf16(ah, bl1, acc[mt][1], 0, 0, 0);
            }
          }
        }
      }

      // ---- cross-wave K-reduction
      if (kw >= 1) {
        float* rp = red + (((kw - 1) << 11) + lane);
#pragma unroll
        for (int mt = 0; mt < 4; ++mt)
#pragma unroll
          for (int nt = 0; nt < 2; ++nt)
#pragma unroll
            for (int r = 0; r < 4; ++r)
              rp[((mt << 3) + (nt << 2) + r) << 6] = acc[mt][nt][r];
      }
      __syncthreads();
      if (kw == 0) {
#pragma unroll
        for (int mt = 0; mt < 4; ++mt)
#pragma unroll
          for (int nt = 0; nt < 2; ++nt)
#pragma unroll
            for (int r = 0; r < 4; ++r) {
              const int idx = ((mt << 3) + (nt << 2) + r) << 6;
              acc[mt][nt][r] += red[idx + lane] + red[2048 + idx + lane] + red[4096 + idx + lane];
            }
        // ---- pointwise; h published via relaxed agent stores (write-through)
        const int wsl = t & RMASK;
        unsigned short* hhi_d = (layer ? h1hi : h0hi) + (wsl << 16);
        unsigned short* hlo_d = (layer ? h1lo : h0lo) + (wsl << 16);
#pragma unroll
        for (int mt = 0; mt < 4; ++mt) {
#pragma unroll
          for (int r = 0; r < 4; ++r) {
            const float a0 = acc[mt][0][r], a1 = acc[mt][1][r];
            const float a0x = __shfl_xor(a0, 8);
            const float a1x = __shfl_xor(a1, 8);
            const bool lo = (cl < 8);
            const float vi = (lo ? a0 : a0x) + bi;
            const float vf = (lo ? a0x : a0) + bf_;
            const float vg = (lo ? a1 : a1x) + bg;
            const float vo = (lo ? a1x : a1) + bo;
            const float ig = sigm(vi), fg = sigm(vf), gg = tanh_(vg), og = sigm(vo);
            const int ci = (mt << 2) + r;
            const float cn = fg * creg[ci] + ig * gg;
            creg[ci] = cn;
            const float h = og * tanh_(cn);
            if (lo) {
              const int b = (mt << 4) + (rg << 2) + r;
              const int hidx = (b << 10) + j0 + u_;
              const unsigned short hb = f2bf(h);
              const unsigned short lb = f2bf(h - bf2f(hb));
              __hip_atomic_store(hhi_d + hidx, hb, __ATOMIC_RELAXED, __HIP_MEMORY_SCOPE_AGENT);
              __hip_atomic_store(hlo_d + hidx, lb, __ATOMIC_RELAXED, __HIP_MEMORY_SCOPE_AGENT);
              if (layer) {
                out[((size_t)b * SEQ + t) * HD + j0 + u_] = h;
                if (t == SEQ - 1) {
                  out[OUT_H + (size_t)(b << 10) + j0 + u_] = h;
                  out[OUT_C + (size_t)(b << 10) + j0 + u_] = cn;
                }
              }
            }
          }
        }
      }
    }
    if (p != SEQ) grid_barrier_flags(flags, go, w, (unsigned)(p + 1), (p & 15) == 15);
  }
}

// prep: combined bias, zero h-ring init slots + barrier flags (every launch)
__global__ void lstm_prep(const float* __restrict__ bih, const float* __restrict__ bhh,
                          float* __restrict__ bias,
                          unsigned short* __restrict__ h0hi, unsigned short* __restrict__ h0lo,
                          unsigned short* __restrict__ h1hi, unsigned short* __restrict__ h1lo,
                          unsigned* __restrict__ bar) {
  const size_t i0 = (size_t)blockIdx.x * blockDim.x + threadIdx.x;
  const size_t stride = (size_t)gridDim.x * blockDim.x;
  for (size_t idx = i0; idx < 8192; idx += stride) bias[idx] = bih[idx] + bhh[idx];
  const ushort4 z = make_ushort4(0, 0, 0, 0);
  const size_t so = ((size_t)RMASK << 16) >> 2;  // slot 31 base in ushort4 units
  for (size_t idx = i0; idx < 16384; idx += stride) {
    ((ushort4*)h0hi)[so + idx] = z; ((ushort4*)h0lo)[so + idx] = z;
    ((ushort4*)h1hi)[so + idx] = z; ((ushort4*)h1lo)[so + idx] = z;
  }
  for (size_t idx = i0; idx < 8256; idx += stride) bar[idx] = 0u;  // flags + go
}

extern "C" void kernel_launch(void* const* d_in, const int* in_sizes, int n_in,
                              void* d_out, int out_size, void* d_ws, size_t ws_size,
                              hipStream_t stream) {
  const float* x     = (const float*)d_in[0];
  const float* Wih_f = (const float*)d_in[1];
  const float* bih   = (const float*)d_in[2];
  const float* Whh_f = (const float*)d_in[3];
  const float* bhh   = (const float*)d_in[4];
  float* out = (float*)d_out;

  char* ws = (char*)d_ws;                                  // ~17 MB used
  float* bias           = (float*)(ws);                    // 32 KB
  unsigned* bar         = (unsigned*)(ws + 65536);         // flags + go (33 KB)
  unsigned* flags       = bar;
  unsigned* go          = bar + 8192;
  unsigned short* h0hi  = (unsigned short*)(ws + (1ull << 20));                 // 4 MB each
  unsigned short* h0lo  = (unsigned short*)(ws + (1ull << 20) + (4ull << 20));
  unsigned short* h1hi  = (unsigned short*)(ws + (1ull << 20) + (8ull << 20));
  unsigned short* h1lo  = (unsigned short*)(ws + (1ull << 20) + (12ull << 20));

  hipLaunchKernelGGL(lstm_prep, dim3(256), dim3(256), 0, stream,
                     bih, bhh, bias, h0hi, h0lo, h1hi, h1lo, bar);

  hipLaunchKernelGGL(lstm_main, dim3(NWG), dim3(TPB), 0, stream,
                     x, Wih_f, Whh_f, bias, h0hi, h0lo, h1hi, h1lo, out, flags, go);
}

// Round 9
// 8853.223 us; speedup vs baseline: 4.4883x; 1.1311x over previous
//
#include <hip/hip_runtime.h>
#include <hip/hip_bf16.h>

#define SEQ 512
#define HD 1024
#define NWG 256
#define TPB 256
#define LDS_RED_OFF 131072
#define LDS_BYTES (131072 + 24576)
#define OUT_H 33554432ull
#define OUT_C 33619968ull
#define RMASK 31   // 32-slot h ring; inv cadence 16 covers slot reuse

typedef __bf16 bf16x8 __attribute__((ext_vector_type(8)));
typedef float f32x4 __attribute__((ext_vector_type(4)));

__device__ __forceinline__ unsigned short f2bf(float f) {
  __hip_bfloat16 b = __float2bfloat16(f);  // RNE
  return __builtin_bit_cast(unsigned short, b);
}
__device__ __forceinline__ float bf2f(unsigned short s) {
  return __builtin_bit_cast(float, (unsigned)s << 16);  // exact widen
}

__device__ __forceinline__ float sigm(float v) { return 1.f / (1.f + __expf(-v)); }
__device__ __forceinline__ float tanh_(float v) {
  float av = fabsf(v);
  float e = __expf(-2.f * av);
  float t = (1.f - e) / (1.f + e);
  return copysignf(t, v);
}

// async global->LDS (cached, aux=0), 16B/lane; LDS dest = wave base + lane*16
__device__ __forceinline__ void gl2lds(const void* g, void* l) {
  __builtin_amdgcn_global_load_lds(
      (const __attribute__((address_space(1))) void*)g,
      (__attribute__((address_space(3))) void*)l, 16, 0, 0);
}

// per-WAVE epoch wait (agent-scope relaxed = L2-bypass poll, no cache ops).
// wave_barrier + memory clobber stop the compiler hoisting gl2lds above it.
__device__ __forceinline__ void wave_wait_ge(const unsigned* a, unsigned v) {
  while (__hip_atomic_load(a, __ATOMIC_RELAXED, __HIP_MEMORY_SCOPE_AGENT) < v)
    __builtin_amdgcn_s_sleep(1);
  __builtin_amdgcn_wave_barrier();
  asm volatile("" ::: "memory");
}

// Persistent LSTM, round-9 structure:
//  - W (hi+lo) in registers; A staged via gl2lds double-buffer (round-7)
//  - h ring (32 slots), relaxed agent h-publish + vmcnt drain (round-8)
//  - DECOUPLED per-layer 128-WG barriers + cross-layer epoch (go0/go1);
//    waits are per-wave: x-waves never wait, h-waves poll only their epoch
//  - x hi/lo split by truncation (cheap VALU)
__global__ __launch_bounds__(TPB, 1) void lstm_main(
    const float* __restrict__ x,
    const float* __restrict__ Wih_f,
    const float* __restrict__ Whh_f,
    const float* __restrict__ bias,
    unsigned short* h0hi, unsigned short* h0lo,
    unsigned short* h1hi, unsigned short* h1lo,
    float* __restrict__ out,
    unsigned* bar) {
  __shared__ char smem[LDS_BYTES];
  float* red = (float*)(smem + LDS_RED_OFF);

  unsigned* go0 = bar + 8192;
  unsigned* go1 = bar + 8192 + 32;

  const int w = blockIdx.x;
  const int tid = threadIdx.x;
  const int layer = w >> 7;
  const int tl = w & 127;             // index within layer; tl==0 is leader
  const int j0 = tl << 3;
  const int lane = tid & 63;
  const int kw = tid >> 6;
  const int cl = lane & 15;
  const int rg = lane >> 4;
  const int kbase = kw << 9;
  const int krel = (kw & 1) << 9;
  const bool isx = (layer == 0) && (kw < 2);

  // ---- W prologue: build hi+lo B-fragments in registers from fp32 W (RNE)
  uint4 whi[32], wlo[32];
#pragma unroll
  for (int i = 0; i < 32; ++i) {
    const int nt = i & 1, ks = i >> 1;
    const int c = nt * 16 + cl;
    const int grow = ((c >> 3) << 10) + j0 + (c & 7);
    const int kglob = kbase + (ks << 5) + (rg << 3);
    const float* src = (kglob < HD)
        ? (Wih_f + (((size_t)layer << 22) + ((size_t)grow << 10) + kglob))
        : (Whh_f + (((size_t)layer << 22) + ((size_t)grow << 10) + (kglob - HD)));
    union { unsigned short s2[8]; uint4 v; } uh, ul;
#pragma unroll
    for (int e = 0; e < 8; ++e) {
      const float vv = src[e];
      const unsigned short hb = f2bf(vv);
      uh.s2[e] = hb;
      ul.s2[e] = f2bf(vv - bf2f(hb));
    }
    whi[i] = uh.v;
    wlo[i] = ul.v;
  }

  const int u_ = cl & 7;
  const float bi  = bias[(layer << 12) + j0 + u_];
  const float bf_ = bias[(layer << 12) + 1024 + j0 + u_];
  const float bg  = bias[(layer << 12) + 2048 + j0 + u_];
  const float bo  = bias[(layer << 12) + 3072 + j0 + u_];

  float creg[16];
#pragma unroll
  for (int i = 0; i < 16; ++i) creg[i] = 0.f;

  // staging lane constants (round-7/8 proven)
  char* stripe = smem + (kw << 14);   // buf0 stripe; buf1 = +65536
  const int hrr = lane >> 3;
  const int hjj = lane & 7;
  const int hsw = hjj ^ hrr;          // pre-swizzled source slot (8 elems each)
  const int xrr = lane >> 4;
  const int xjj = lane & 15;
  const int xslotE = xjj ^ xrr;       // even issues
  const int xslotO = xjj ^ (4 + xrr); // odd issues

  __syncthreads();

  for (int t = 0; t < SEQ; ++t) {
    const unsigned e = (unsigned)(t + 1);

    // ---- per-wave epoch gating (x-waves: none)
    if (layer == 0) {
      if (kw >= 2) wave_wait_ge(go0, (unsigned)t);          // h0[t-1]
    } else {
      if (kw < 2) wave_wait_ge(go0, e);                     // h0[t]
      else        wave_wait_ge(go1, (unsigned)t);           // h1[t-1]
    }

    f32x4 acc[4][2];
#pragma unroll
    for (int mt = 0; mt < 4; ++mt) {
      acc[mt][0] = (f32x4){0.f, 0.f, 0.f, 0.f};
      acc[mt][1] = (f32x4){0.f, 0.f, 0.f, 0.f};
    }

    if (isx) {
      // ---- x path: stage raw fp32, trunc-split hi/lo after LDS read
      const float* pxE = x + ((size_t)(xrr * SEQ + t) << 10) + kbase + (xslotE << 2);
      const float* pxO = x + ((size_t)(xrr * SEQ + t) << 10) + kbase + (xslotO << 2);
#pragma unroll
      for (int i = 0; i < 16; ++i)
        gl2lds(((i & 1) ? pxO : pxE) + (size_t)i * 2097152, stripe + i * 1024);
#pragma unroll
      for (int s = 0; s < 8; ++s) {
        char* cb = stripe + ((s & 1) << 16);
        if (s < 7) {
          char* nb = stripe + (((s + 1) & 1) << 16);
          const int so = (s + 1) << 6;
#pragma unroll
          for (int i = 0; i < 16; ++i)
            gl2lds(((i & 1) ? pxO : pxE) + (size_t)i * 2097152 + so, nb + i * 1024);
          asm volatile("s_waitcnt vmcnt(16)" ::: "memory");
        } else {
          asm volatile("s_waitcnt vmcnt(0)" ::: "memory");
        }
#pragma unroll
        for (int ksl = 0; ksl < 2; ++ksl) {
          const int ig = (((s << 1) + ksl) << 1);
          const bf16x8 bh0 = __builtin_bit_cast(bf16x8, whi[ig]);
          const bf16x8 bh1 = __builtin_bit_cast(bf16x8, whi[ig + 1]);
          const bf16x8 bl0 = __builtin_bit_cast(bf16x8, wlo[ig]);
          const bf16x8 bl1 = __builtin_bit_cast(bf16x8, wlo[ig + 1]);
#pragma unroll
          for (int mt = 0; mt < 4; ++mt) {
            const int r = (mt << 4) + cl;
            const int a0 = (ksl << 3) + (rg << 1);
            const float4 f0 = *(const float4*)(cb + r * 256 + ((a0 ^ (cl & 7)) << 4));
            const float4 f1 = *(const float4*)(cb + r * 256 + (((a0 + 1) ^ (cl & 7)) << 4));
            union { unsigned short s2[8]; uint4 v; } uh, ul;
            const float ee[8] = {f0.x, f0.y, f0.z, f0.w, f1.x, f1.y, f1.z, f1.w};
#pragma unroll
            for (int e2 = 0; e2 < 8; ++e2) {
              const unsigned uu = __builtin_bit_cast(unsigned, ee[e2]);
              uh.s2[e2] = (unsigned short)(uu >> 16);  // trunc16 == exact bf16
              ul.s2[e2] = f2bf(ee[e2] - __builtin_bit_cast(float, uu & 0xffff0000u));
            }
            const bf16x8 ah = __builtin_bit_cast(bf16x8, uh.v);
            const bf16x8 al = __builtin_bit_cast(bf16x8, ul.v);
            acc[mt][0] = __builtin_amdgcn_mfma_f32_16x16x32_bf16(ah, bh0, acc[mt][0], 0, 0, 0);
            acc[mt][1] = __builtin_amdgcn_mfma_f32_16x16x32_bf16(ah, bh1, acc[mt][1], 0, 0, 0);
            acc[mt][0] = __builtin_amdgcn_mfma_f32_16x16x32_bf16(al, bh0, acc[mt][0], 0, 0, 0);
            acc[mt][1] = __builtin_amdgcn_mfma_f32_16x16x32_bf16(al, bh1, acc[mt][1], 0, 0, 0);
            acc[mt][0] = __builtin_amdgcn_mfma_f32_16x16x32_bf16(ah, bl0, acc[mt][0], 0, 0, 0);
            acc[mt][1] = __builtin_amdgcn_mfma_f32_16x16x32_bf16(ah, bl1, acc[mt][1], 0, 0, 0);
          }
        }
      }
    } else {
      // ---- h path: stage bf16 hi+lo stripes from ring slot (cached reads)
      const unsigned short *shi_, *slo_;
      if (layer == 0) {
        const int sl = (t - 1) & RMASK;
        shi_ = h0hi + (sl << 16); slo_ = h0lo + (sl << 16);
      } else if (kw < 2) {
        const int sl = t & RMASK;
        shi_ = h0hi + (sl << 16); slo_ = h0lo + (sl << 16);
      } else {
        const int sl = (t - 1) & RMASK;
        shi_ = h1hi + (sl << 16); slo_ = h1lo + (sl << 16);
      }
      const unsigned short* ph = shi_ + (hrr << 10) + krel + (hsw << 3);
      const unsigned short* pl = slo_ + (hrr << 10) + krel + (hsw << 3);
#pragma unroll
      for (int i = 0; i < 8; ++i) {
        gl2lds(ph + i * 8192, stripe + i * 1024);
        gl2lds(pl + i * 8192, stripe + 8192 + i * 1024);
      }
#pragma unroll
      for (int s = 0; s < 8; ++s) {
        char* cb = stripe + ((s & 1) << 16);
        if (s < 7) {
          char* nb = stripe + (((s + 1) & 1) << 16);
          const int so = (s + 1) << 6;
#pragma unroll
          for (int i = 0; i < 8; ++i) {
            gl2lds(ph + so + i * 8192, nb + i * 1024);
            gl2lds(pl + so + i * 8192, nb + 8192 + i * 1024);
          }
          asm volatile("s_waitcnt vmcnt(16)" ::: "memory");
        } else {
          asm volatile("s_waitcnt vmcnt(0)" ::: "memory");
        }
#pragma unroll
        for (int ksl = 0; ksl < 2; ++ksl) {
          const int ig = (((s << 1) + ksl) << 1);
          const bf16x8 bh0 = __builtin_bit_cast(bf16x8, whi[ig]);
          const bf16x8 bh1 = __builtin_bit_cast(bf16x8, whi[ig + 1]);
          const bf16x8 bl0 = __builtin_bit_cast(bf16x8, wlo[ig]);
          const bf16x8 bl1 = __builtin_bit_cast(bf16x8, wlo[ig + 1]);
#pragma unroll
          for (int mt = 0; mt < 4; ++mt) {
            const int r = (mt << 4) + cl;
            const unsigned off = (unsigned)(r << 7) +
                (unsigned)(((((ksl << 2) + rg)) ^ (cl & 7)) << 4);
            const bf16x8 ah = __builtin_bit_cast(bf16x8, *(const uint4*)(cb + off));
            const bf16x8 al = __builtin_bit_cast(bf16x8, *(const uint4*)(cb + 8192 + off));
            acc[mt][0] = __builtin_amdgcn_mfma_f32_16x16x32_bf16(ah, bh0, acc[mt][0], 0, 0, 0);
            acc[mt][1] = __builtin_amdgcn_mfma_f32_16x16x32_bf16(ah, bh1, acc[mt][1], 0, 0, 0);
            acc[mt][0] = __builtin_amdgcn_mfma_f32_16x16x32_bf16(al, bh0, acc[mt][0], 0, 0, 0);
            acc[mt][1] = __builtin_amdgcn_mfma_f32_16x16x32_bf16(al, bh1, acc[mt][1], 0, 0, 0);
            acc[mt][0] = __builtin_amdgcn_mfma_f32_16x16x32_bf16(ah, bl0, acc[mt][0], 0, 0, 0);
            acc[mt][1] = __builtin_amdgcn_mfma_f32_16x16x32_bf16(ah, bl1, acc[mt][1], 0, 0, 0);
          }
        }
      }
    }

    // ---- cross-wave K-reduction (red protected by sync #1/#2)
    if (kw >= 1) {
      float* rp = red + (((kw - 1) << 11) + lane);
#pragma unroll
      for (int mt = 0; mt < 4; ++mt)
#pragma unroll
        for (int nt = 0; nt < 2; ++nt)
#pragma unroll
          for (int r = 0; r < 4; ++r)
            rp[((mt << 3) + (nt << 2) + r) << 6] = acc[mt][nt][r];
    }
    __syncthreads();  // #1: dumps visible to kw0
    if (kw == 0) {
#pragma unroll
      for (int mt = 0; mt < 4; ++mt)
#pragma unroll
        for (int nt = 0; nt < 2; ++nt)
#pragma unroll
          for (int r = 0; r < 4; ++r) {
            const int idx = ((mt << 3) + (nt << 2) + r) << 6;
            acc[mt][nt][r] += red[idx + lane] + red[2048 + idx + lane] + red[4096 + idx + lane];
          }
    }
    __syncthreads();  // #2: kw0 done reading red; other waves may proceed

    if (kw == 0) {
      // ring guard: don't overwrite h0[t] (slot t&31) until L1 consumed h0[t-32]
      if (layer == 0 && t >= 32) wave_wait_ge(go1, (unsigned)(t - 31));
      const int wsl = t & RMASK;
      unsigned short* hhi_d = (layer ? h1hi : h0hi) + (wsl << 16);
      unsigned short* hlo_d = (layer ? h1lo : h0lo) + (wsl << 16);
#pragma unroll
      for (int mt = 0; mt < 4; ++mt) {
#pragma unroll
        for (int r = 0; r < 4; ++r) {
          const float a0 = acc[mt][0][r], a1 = acc[mt][1][r];
          const float a0x = __shfl_xor(a0, 8);
          const float a1x = __shfl_xor(a1, 8);
          const bool lo = (cl < 8);
          const float vi = (lo ? a0 : a0x) + bi;
          const float vf = (lo ? a0x : a0) + bf_;
          const float vg = (lo ? a1 : a1x) + bg;
          const float vo = (lo ? a1x : a1) + bo;
          const float ig = sigm(vi), fg = sigm(vf), gg = tanh_(vg), og = sigm(vo);
          const int ci = (mt << 2) + r;
          const float cn = fg * creg[ci] + ig * gg;
          creg[ci] = cn;
          const float h = og * tanh_(cn);
          if (lo) {
            const int b = (mt << 4) + (rg << 2) + r;
            const int hidx = (b << 10) + j0 + u_;
            const unsigned short hb = f2bf(h);
            const unsigned short lb = f2bf(h - bf2f(hb));
            __hip_atomic_store(hhi_d + hidx, hb, __ATOMIC_RELAXED, __HIP_MEMORY_SCOPE_AGENT);
            __hip_atomic_store(hlo_d + hidx, lb, __ATOMIC_RELAXED, __HIP_MEMORY_SCOPE_AGENT);
            if (layer) {
              out[((size_t)b * SEQ + t) * HD + j0 + u_] = h;
              if (t == SEQ - 1) {
                out[OUT_H + (size_t)(b << 10) + j0 + u_] = h;
                out[OUT_C + (size_t)(b << 10) + j0 + u_] = cn;
              }
            }
          }
        }
      }
      asm volatile("s_waitcnt vmcnt(0)" ::: "memory");  // drain h/out publishes
      if (lane == 0)
        __hip_atomic_store(bar + (w << 5), e, __ATOMIC_RELAXED, __HIP_MEMORY_SCOPE_AGENT);
    }

    // ---- layer leader: gather 127 peer flags, publish layer epoch
    if (tl == 0) {
      __syncthreads();  // own kw0 flag stored (lane0 passed vmcnt+store)
      if (tid >= 1 && tid < 128) {
        const unsigned* pf = bar + (((layer << 7) + tid) << 5);
        while (__hip_atomic_load(pf, __ATOMIC_RELAXED, __HIP_MEMORY_SCOPE_AGENT) < e)
          __builtin_amdgcn_s_sleep(1);
      }
      __syncthreads();
      if (tid == 0)
        __hip_atomic_store(layer ? go1 : go0, e, __ATOMIC_RELAXED, __HIP_MEMORY_SCOPE_AGENT);
    }

    // ---- periodic L2 invalidate: covers h-ring slot reuse (2 invs / 32 steps)
    if ((t & 15) == 15) __builtin_amdgcn_fence(__ATOMIC_ACQUIRE, "agent");
  }
}

// prep: combined bias, zero h-ring init slots + flags/epochs (every launch)
__global__ void lstm_prep(const float* __restrict__ bih, const float* __restrict__ bhh,
                          float* __restrict__ bias,
                          unsigned short* __restrict__ h0hi, unsigned short* __restrict__ h0lo,
                          unsigned short* __restrict__ h1hi, unsigned short* __restrict__ h1lo,
                          unsigned* __restrict__ bar) {
  const size_t i0 = (size_t)blockIdx.x * blockDim.x + threadIdx.x;
  const size_t stride = (size_t)gridDim.x * blockDim.x;
  for (size_t idx = i0; idx < 8192; idx += stride) bias[idx] = bih[idx] + bhh[idx];
  const ushort4 z = make_ushort4(0, 0, 0, 0);
  const size_t so = ((size_t)RMASK << 16) >> 2;  // slot 31 base in ushort4 units
  for (size_t idx = i0; idx < 16384; idx += stride) {
    ((ushort4*)h0hi)[so + idx] = z; ((ushort4*)h0lo)[so + idx] = z;
    ((ushort4*)h1hi)[so + idx] = z; ((ushort4*)h1lo)[so + idx] = z;
  }
  for (size_t idx = i0; idx < 8256; idx += stride) bar[idx] = 0u;  // flags + go0/go1
}

extern "C" void kernel_launch(void* const* d_in, const int* in_sizes, int n_in,
                              void* d_out, int out_size, void* d_ws, size_t ws_size,
                              hipStream_t stream) {
  const float* x     = (const float*)d_in[0];
  const float* Wih_f = (const float*)d_in[1];
  const float* bih   = (const float*)d_in[2];
  const float* Whh_f = (const float*)d_in[3];
  const float* bhh   = (const float*)d_in[4];
  float* out = (float*)d_out;

  char* ws = (char*)d_ws;                                  // ~17 MB used
  float* bias           = (float*)(ws);                    // 32 KB
  unsigned* bar         = (unsigned*)(ws + 65536);         // flags + epochs (33 KB)
  unsigned short* h0hi  = (unsigned short*)(ws + (1ull << 20));                 // 4 MB each
  unsigned short* h0lo  = (unsigned short*)(ws + (1ull << 20) + (4ull << 20));
  unsigned short* h1hi  = (unsigned short*)(ws + (1ull << 20) + (8ull << 20));
  unsigned short* h1lo  = (unsigned short*)(ws + (1ull << 20) + (12ull << 20));

  hipLaunchKernelGGL(lstm_prep, dim3(256), dim3(256), 0, stream,
                     bih, bhh, bias, h0hi, h0lo, h1hi, h1lo, bar);

  hipLaunchKernelGGL(lstm_main, dim3(NWG), dim3(TPB), 0, stream,
                     x, Wih_f, Whh_f, bias, h0hi, h0lo, h1hi, h1lo, out, bar);
}

// Round 12
// 7847.166 us; speedup vs baseline: 5.0638x; 1.1282x over previous
//
#include <hip/hip_runtime.h>
#include <hip/hip_bf16.h>

#define SEQ 512
#define HD 1024
#define NWG 256
#define TPB 256
#define RED_OFF 131072
#define LDS_BYTES (131072 + 32768)
#define OUT_H 33554432ull
#define OUT_C 33619968ull
#define RMASK 31   // 32-slot h ring; inv cadence 16 covers slot reuse

typedef __bf16 bf16x8 __attribute__((ext_vector_type(8)));
typedef float f32x4 __attribute__((ext_vector_type(4)));

__device__ __forceinline__ unsigned short f2bf(float f) {
  __hip_bfloat16 b = __float2bfloat16(f);  // RNE
  return __builtin_bit_cast(unsigned short, b);
}
__device__ __forceinline__ float bf2f(unsigned short s) {
  return __builtin_bit_cast(float, (unsigned)s << 16);  // exact widen
}

__device__ __forceinline__ float sigm(float v) { return 1.f / (1.f + __expf(-v)); }
__device__ __forceinline__ float tanh_(float v) {
  float av = fabsf(v);
  float e = __expf(-2.f * av);
  float t = (1.f - e) / (1.f + e);
  return copysignf(t, v);
}

// async global->LDS, 16B/lane; global src per-lane, LDS dest wave-uniform base
__device__ __forceinline__ void gl2lds(const void* g, void* l) {
  __builtin_amdgcn_global_load_lds(
      (const __attribute__((address_space(1))) void*)g,
      (__attribute__((address_space(3))) void*)l, 16, 0, 0);
}

// per-WAVE epoch wait (relaxed agent poll; no cache maintenance)
__device__ __forceinline__ void wave_wait_ge(const unsigned* a, unsigned v) {
  while (__hip_atomic_load(a, __ATOMIC_RELAXED, __HIP_MEMORY_SCOPE_AGENT) < v)
    __builtin_amdgcn_s_sleep(1);
  __builtin_amdgcn_wave_barrier();
  asm volatile("" ::: "memory");
}

// Persistent LSTM, round-12: round-9 proven core (4 waves, K-split 4, gl2lds
// double-buffer staging, decoupled per-layer barriers, h-ring relaxed publish)
// + SYMMETRIC EPILOGUE: all 4 waves dump acc to red (4 slots); wave kw
// finishes row-tile mt=kw (reduction, pointwise, stores) -> serial tail /4.
// Summation order s0+s1+s2+s3 == round 9 -> bit-identical numerics.
__global__ __launch_bounds__(TPB, 1) void lstm_main(
    const float* __restrict__ x,
    const float* __restrict__ Wih_f,
    const float* __restrict__ Whh_f,
    const float* __restrict__ bias,
    unsigned short* h0hi, unsigned short* h0lo,
    unsigned short* h1hi, unsigned short* h1lo,
    float* __restrict__ out,
    unsigned* bar) {
  __shared__ char smem[LDS_BYTES];
  float* red = (float*)(smem + RED_OFF);

  unsigned* go0 = bar + 8192;
  unsigned* go1 = bar + 8192 + 32;

  const int w = blockIdx.x;
  const int tid = threadIdx.x;
  const int layer = w >> 7;
  const int tl = w & 127;             // index within layer; tl==0 is leader
  const int j0 = tl << 3;
  const int lane = tid & 63;
  const int kw = tid >> 6;
  const int cl = lane & 15;
  const int rg = lane >> 4;
  const int kbase = kw << 9;
  const int krel = (kw & 1) << 9;
  const bool isx = (layer == 0) && (kw < 2);

  // ---- W prologue: build hi+lo B-fragments in registers from fp32 W (RNE)
  uint4 whi[32], wlo[32];
#pragma unroll
  for (int i = 0; i < 32; ++i) {
    const int nt = i & 1, ks = i >> 1;
    const int c = nt * 16 + cl;
    const int grow = ((c >> 3) << 10) + j0 + (c & 7);
    const int kglob = kbase + (ks << 5) + (rg << 3);
    const float* src = (kglob < HD)
        ? (Wih_f + (((size_t)layer << 22) + ((size_t)grow << 10) + kglob))
        : (Whh_f + (((size_t)layer << 22) + ((size_t)grow << 10) + (kglob - HD)));
    union { unsigned short s2[8]; uint4 v; } uh, ul;
#pragma unroll
    for (int e = 0; e < 8; ++e) {
      const float vv = src[e];
      const unsigned short hb = f2bf(vv);
      uh.s2[e] = hb;
      ul.s2[e] = f2bf(vv - bf2f(hb));
    }
    whi[i] = uh.v;
    wlo[i] = ul.v;
  }

  const int u_ = cl & 7;
  const float bi  = bias[(layer << 12) + j0 + u_];
  const float bf_ = bias[(layer << 12) + 1024 + j0 + u_];
  const float bg  = bias[(layer << 12) + 2048 + j0 + u_];
  const float bo  = bias[(layer << 12) + 3072 + j0 + u_];

  float creg[4];
#pragma unroll
  for (int i = 0; i < 4; ++i) creg[i] = 0.f;

  // staging lane constants (round-7/8/9 proven)
  char* stripe = smem + (kw << 14);   // buf0 stripe; buf1 = +65536
  const int hrr = lane >> 3;
  const int hjj = lane & 7;
  const int hsw = hjj ^ hrr;          // pre-swizzled source slot (8 elems each)
  const int xrr = lane >> 4;
  const int xjj = lane & 15;
  const int xslotE = xjj ^ xrr;       // even issues
  const int xslotO = xjj ^ (4 + xrr); // odd issues

  __syncthreads();

  for (int t = 0; t < SEQ; ++t) {
    const unsigned e = (unsigned)(t + 1);

    // ---- per-wave epoch gating (L0 x-waves: none)
    if (layer == 0) {
      if (kw >= 2) wave_wait_ge(go0, (unsigned)t);          // h0[t-1]
    } else {
      if (kw < 2) wave_wait_ge(go0, e);                     // h0[t]
      else        wave_wait_ge(go1, (unsigned)t);           // h1[t-1]
    }

    f32x4 acc[4][2];
#pragma unroll
    for (int mt = 0; mt < 4; ++mt) {
      acc[mt][0] = (f32x4){0.f, 0.f, 0.f, 0.f};
      acc[mt][1] = (f32x4){0.f, 0.f, 0.f, 0.f};
    }

    if (isx) {
      // ---- x path: stage raw fp32, trunc-split hi/lo after LDS read
      const float* pxE = x + ((size_t)(xrr * SEQ + t) << 10) + kbase + (xslotE << 2);
      const float* pxO = x + ((size_t)(xrr * SEQ + t) << 10) + kbase + (xslotO << 2);
#pragma unroll
      for (int i = 0; i < 16; ++i)
        gl2lds(((i & 1) ? pxO : pxE) + (size_t)i * 2097152, stripe + i * 1024);
#pragma unroll
      for (int s = 0; s < 8; ++s) {
        char* cb = stripe + ((s & 1) << 16);
        if (s < 7) {
          char* nb = stripe + (((s + 1) & 1) << 16);
          const int so = (s + 1) << 6;
#pragma unroll
          for (int i = 0; i < 16; ++i)
            gl2lds(((i & 1) ? pxO : pxE) + (size_t)i * 2097152 + so, nb + i * 1024);
          asm volatile("s_waitcnt vmcnt(16)" ::: "memory");
        } else {
          asm volatile("s_waitcnt vmcnt(0)" ::: "memory");
        }
#pragma unroll
        for (int ksl = 0; ksl < 2; ++ksl) {
          const int ig = (((s << 1) + ksl) << 1);
          const bf16x8 bh0 = __builtin_bit_cast(bf16x8, whi[ig]);
          const bf16x8 bh1 = __builtin_bit_cast(bf16x8, whi[ig + 1]);
          const bf16x8 bl0 = __builtin_bit_cast(bf16x8, wlo[ig]);
          const bf16x8 bl1 = __builtin_bit_cast(bf16x8, wlo[ig + 1]);
#pragma unroll
          for (int mt = 0; mt < 4; ++mt) {
            const int r = (mt << 4) + cl;
            const int a0 = (ksl << 3) + (rg << 1);
            const float4 f0 = *(const float4*)(cb + r * 256 + ((a0 ^ (cl & 7)) << 4));
            const float4 f1 = *(const float4*)(cb + r * 256 + (((a0 + 1) ^ (cl & 7)) << 4));
            union { unsigned short s2[8]; uint4 v; } uh, ul;
            const float ee[8] = {f0.x, f0.y, f0.z, f0.w, f1.x, f1.y, f1.z, f1.w};
#pragma unroll
            for (int e2 = 0; e2 < 8; ++e2) {
              const unsigned uu = __builtin_bit_cast(unsigned, ee[e2]);
              uh.s2[e2] = (unsigned short)(uu >> 16);  // trunc16 = exact bf16 hi
              ul.s2[e2] = f2bf(ee[e2] - __builtin_bit_cast(float, uu & 0xffff0000u));
            }
            const bf16x8 ah = __builtin_bit_cast(bf16x8, uh.v);
            const bf16x8 al = __builtin_bit_cast(bf16x8, ul.v);
            acc[mt][0] = __builtin_amdgcn_mfma_f32_16x16x32_bf16(ah, bh0, acc[mt][0], 0, 0, 0);
            acc[mt][1] = __builtin_amdgcn_mfma_f32_16x16x32_bf16(ah, bh1, acc[mt][1], 0, 0, 0);
            acc[mt][0] = __builtin_amdgcn_mfma_f32_16x16x32_bf16(al, bh0, acc[mt][0], 0, 0, 0);
            acc[mt][1] = __builtin_amdgcn_mfma_f32_16x16x32_bf16(al, bh1, acc[mt][1], 0, 0, 0);
            acc[mt][0] = __builtin_amdgcn_mfma_f32_16x16x32_bf16(ah, bl0, acc[mt][0], 0, 0, 0);
            acc[mt][1] = __builtin_amdgcn_mfma_f32_16x16x32_bf16(ah, bl1, acc[mt][1], 0, 0, 0);
          }
        }
      }
    } else {
      // ---- h path: stage bf16 hi+lo stripes from ring slot (cached reads)
      const unsigned short *shi_, *slo_;
      if (layer == 0) {
        const int sl = (t - 1) & RMASK;
        shi_ = h0hi + (sl << 16); slo_ = h0lo + (sl << 16);
      } else if (kw < 2) {
        const int sl = t & RMASK;
        shi_ = h0hi + (sl << 16); slo_ = h0lo + (sl << 16);
      } else {
        const int sl = (t - 1) & RMASK;
        shi_ = h1hi + (sl << 16); slo_ = h1lo + (sl << 16);
      }
      const unsigned short* ph = shi_ + (hrr << 10) + krel + (hsw << 3);
      const unsigned short* pl = slo_ + (hrr << 10) + krel + (hsw << 3);
#pragma unroll
      for (int i = 0; i < 8; ++i) {
        gl2lds(ph + i * 8192, stripe + i * 1024);
        gl2lds(pl + i * 8192, stripe + 8192 + i * 1024);
      }
#pragma unroll
      for (int s = 0; s < 8; ++s) {
        char* cb = stripe + ((s & 1) << 16);
        if (s < 7) {
          char* nb = stripe + (((s + 1) & 1) << 16);
          const int so = (s + 1) << 6;
#pragma unroll
          for (int i = 0; i < 8; ++i) {
            gl2lds(ph + so + i * 8192, nb + i * 1024);
            gl2lds(pl + so + i * 8192, nb + 8192 + i * 1024);
          }
          asm volatile("s_waitcnt vmcnt(16)" ::: "memory");
        } else {
          asm volatile("s_waitcnt vmcnt(0)" ::: "memory");
        }
#pragma unroll
        for (int ksl = 0; ksl < 2; ++ksl) {
          const int ig = (((s << 1) + ksl) << 1);
          const bf16x8 bh0 = __builtin_bit_cast(bf16x8, whi[ig]);
          const bf16x8 bh1 = __builtin_bit_cast(bf16x8, whi[ig + 1]);
          const bf16x8 bl0 = __builtin_bit_cast(bf16x8, wlo[ig]);
          const bf16x8 bl1 = __builtin_bit_cast(bf16x8, wlo[ig + 1]);
#pragma unroll
          for (int mt = 0; mt < 4; ++mt) {
            const int r = (mt << 4) + cl;
            const unsigned off = (unsigned)(r << 7) +
                (unsigned)(((((ksl << 2) + rg)) ^ (cl & 7)) << 4);
            const bf16x8 ah = __builtin_bit_cast(bf16x8, *(const uint4*)(cb + off));
            const bf16x8 al = __builtin_bit_cast(bf16x8, *(const uint4*)(cb + 8192 + off));
            acc[mt][0] = __builtin_amdgcn_mfma_f32_16x16x32_bf16(ah, bh0, acc[mt][0], 0, 0, 0);
            acc[mt][1] = __builtin_amdgcn_mfma_f32_16x16x32_bf16(ah, bh1, acc[mt][1], 0, 0, 0);
            acc[mt][0] = __builtin_amdgcn_mfma_f32_16x16x32_bf16(al, bh0, acc[mt][0], 0, 0, 0);
            acc[mt][1] = __builtin_amdgcn_mfma_f32_16x16x32_bf16(al, bh1, acc[mt][1], 0, 0, 0);
            acc[mt][0] = __builtin_amdgcn_mfma_f32_16x16x32_bf16(ah, bl0, acc[mt][0], 0, 0, 0);
            acc[mt][1] = __builtin_amdgcn_mfma_f32_16x16x32_bf16(ah, bl1, acc[mt][1], 0, 0, 0);
          }
        }
      }
    }

    // ---- symmetric epilogue: every wave dumps full acc to slot kw
    {
      float* rp = red + (kw << 11) + lane;
#pragma unroll
      for (int mt = 0; mt < 4; ++mt)
#pragma unroll
        for (int nt = 0; nt < 2; ++nt)
#pragma unroll
          for (int r = 0; r < 4; ++r)
            rp[((mt << 3) + (nt << 2) + r) << 6] = acc[mt][nt][r];
    }
    __syncthreads();  // R1: all dumps visible

    {
      // wave kw finishes row-tile mt=kw: sum slots 0..3 (order == round 9)
      float g0[4], g1[4];
#pragma unroll
      for (int r = 0; r < 4; ++r) {
        const int i0x = (((kw << 3) + r) << 6) + lane;
        const int i1x = (((kw << 3) + 4 + r) << 6) + lane;
        g0[r] = red[i0x] + red[2048 + i0x] + red[4096 + i0x] + red[6144 + i0x];
        g1[r] = red[i1x] + red[2048 + i1x] + red[4096 + i1x] + red[6144 + i1x];
      }
      // ring guard: don't overwrite h slot until consumer within 32 steps
      if (layer == 0 && t >= 32) wave_wait_ge(go1, (unsigned)(t - 31));
      const int wsl = t & RMASK;
      unsigned short* hhi_d = (layer ? h1hi : h0hi) + (wsl << 16);
      unsigned short* hlo_d = (layer ? h1lo : h0lo) + (wsl << 16);
#pragma unroll
      for (int r = 0; r < 4; ++r) {
        const float a0 = g0[r], a1 = g1[r];
        const float a0x = __shfl_xor(a0, 8);
        const float a1x = __shfl_xor(a1, 8);
        const bool lo = (cl < 8);
        const float vi = (lo ? a0 : a0x) + bi;
        const float vf = (lo ? a0x : a0) + bf_;
        const float vg = (lo ? a1 : a1x) + bg;
        const float vo = (lo ? a1x : a1) + bo;
        const float ig = sigm(vi), fg = sigm(vf), gg = tanh_(vg), og = sigm(vo);
        const float cn = fg * creg[r] + ig * gg;
        creg[r] = cn;
        const float h = og * tanh_(cn);
        if (lo) {
          const int b = (kw << 4) + (rg << 2) + r;
          const int hidx = (b << 10) + j0 + u_;
          const unsigned short hb = f2bf(h);
          const unsigned short lb = f2bf(h - bf2f(hb));
          __hip_atomic_store(hhi_d + hidx, hb, __ATOMIC_RELAXED, __HIP_MEMORY_SCOPE_AGENT);
          __hip_atomic_store(hlo_d + hidx, lb, __ATOMIC_RELAXED, __HIP_MEMORY_SCOPE_AGENT);
          if (layer) {
            out[((size_t)b * SEQ + t) * HD + j0 + u_] = h;
            if (t == SEQ - 1) {
              out[OUT_H + (size_t)(b << 10) + j0 + u_] = h;
              out[OUT_C + (size_t)(b << 10) + j0 + u_] = cn;
            }
          }
        }
      }
      asm volatile("s_waitcnt vmcnt(0)" ::: "memory");  // drain own publishes
    }
    __syncthreads();  // R2: all waves' publishes drained; red free for t+1

    if (tid == 0)
      __hip_atomic_store(bar + (w << 5), e, __ATOMIC_RELAXED, __HIP_MEMORY_SCOPE_AGENT);

    // ---- layer leader: gather 127 peer flags, publish layer epoch
    if (tl == 0) {
      __syncthreads();  // own flag stored (tid0 passed store above)
      if (tid >= 1 && tid < 128) {
        const unsigned* pf = bar + (((layer << 7) + tid) << 5);
        while (__hip_atomic_load(pf, __ATOMIC_RELAXED, __HIP_MEMORY_SCOPE_AGENT) < e)
          __builtin_amdgcn_s_sleep(1);
      }
      __syncthreads();
      if (tid == 0)
        __hip_atomic_store(layer ? go1 : go0, e, __ATOMIC_RELAXED, __HIP_MEMORY_SCOPE_AGENT);
    }

    // ---- periodic L2 invalidate: covers h-ring slot reuse (2 invs / 32 steps)
    if ((t & 15) == 15) __builtin_amdgcn_fence(__ATOMIC_ACQUIRE, "agent");
  }
}

// prep: combined bias, zero h-ring init slot + flags/epochs (every launch)
__global__ void lstm_prep(const float* __restrict__ bih, const float* __restrict__ bhh,
                          float* __restrict__ bias,
                          unsigned short* __restrict__ h0hi, unsigned short* __restrict__ h0lo,
                          unsigned short* __restrict__ h1hi, unsigned short* __restrict__ h1lo,
                          unsigned* __restrict__ bar) {
  const size_t i0 = (size_t)blockIdx.x * blockDim.x + threadIdx.x;
  const size_t stride = (size_t)gridDim.x * blockDim.x;
  for (size_t idx = i0; idx < 8192; idx += stride) bias[idx] = bih[idx] + bhh[idx];
  const ushort4 z = make_ushort4(0, 0, 0, 0);
  const size_t so = ((size_t)RMASK << 16) >> 2;  // slot 31 base in ushort4 units
  for (size_t idx = i0; idx < 16384; idx += stride) {
    ((ushort4*)h0hi)[so + idx] = z; ((ushort4*)h0lo)[so + idx] = z;
    ((ushort4*)h1hi)[so + idx] = z; ((ushort4*)h1lo)[so + idx] = z;
  }
  for (size_t idx = i0; idx < 8256; idx += stride) bar[idx] = 0u;  // flags + go0/go1
}

extern "C" void kernel_launch(void* const* d_in, const int* in_sizes, int n_in,
                              void* d_out, int out_size, void* d_ws, size_t ws_size,
                              hipStream_t stream) {
  const float* x     = (const float*)d_in[0];
  const float* Wih_f = (const float*)d_in[1];
  const float* bih   = (const float*)d_in[2];
  const float* Whh_f = (const float*)d_in[3];
  const float* bhh   = (const float*)d_in[4];
  float* out = (float*)d_out;

  char* ws = (char*)d_ws;                                  // ~17 MB used
  float* bias           = (float*)(ws);                    // 32 KB
  unsigned* bar         = (unsigned*)(ws + 65536);         // flags + epochs (33 KB)
  unsigned short* h0hi  = (unsigned short*)(ws + (1ull << 20));                 // 4 MB each
  unsigned short* h0lo  = (unsigned short*)(ws + (1ull << 20) + (4ull << 20));
  unsigned short* h1hi  = (unsigned short*)(ws + (1ull << 20) + (8ull << 20));
  unsigned short* h1lo  = (unsigned short*)(ws + (1ull << 20) + (12ull << 20));

  hipLaunchKernelGGL(lstm_prep, dim3(256), dim3(256), 0, stream,
                     bih, bhh, bias, h0hi, h0lo, h1hi, h1lo, bar);

  hipLaunchKernelGGL(lstm_main, dim3(NWG), dim3(TPB), 0, stream,
                     x, Wih_f, Whh_f, bias, h0hi, h0lo, h1hi, h1lo, out, bar);
}